// Round 13
// baseline (212.752 us; speedup 1.0000x reference)
//
#include <hip/hip_runtime.h>
#include <math.h>

// Problem constants
#define NB 4
#define NC 64
#define NPTS 4096
#define NROWS (NB*NPTS)      // 16384

typedef __attribute__((ext_vector_type(4))) float f32x4;
typedef __bf16 bf16x8 __attribute__((ext_vector_type(8)));

__device__ __forceinline__ ushort f2bf(float f) {
  unsigned u = __float_as_uint(f);
  u = (u + 0x7FFFu + ((u >> 16) & 1u)) >> 16;   // RNE
  return (ushort)u;
}
__device__ __forceinline__ unsigned pk2(float lo, float hi) {
  return (unsigned)f2bf(lo) | ((unsigned)f2bf(hi) << 16);
}

// ---------------- top-16 insertion (sorted ascending, dd[15]=max) -------------
__device__ __forceinline__ void insert16(double dist, int j, double (&dd)[16], int (&ii)[16]) {
  double cd = dist; int ci = j;
#pragma unroll
  for (int s = 0; s < 16; ++s) {
    double od = dd[s]; int oi = ii[s];
    bool c = cd < od;
    dd[s] = c ? cd : od;
    ii[s] = c ? ci : oi;
    cd = c ? od : cd;
    ci = c ? oi : ci;
  }
}

__device__ __forceinline__ void bub24(unsigned key, unsigned (&top)[24]) {
#pragma unroll
  for (int q2 = 0; q2 < 24; ++q2) {
    unsigned lo = min(key, top[q2]);
    key = max(key, top[q2]);
    top[q2] = lo;
  }
}

__device__ __forceinline__ double wave_reduce(double v) {
#pragma unroll
  for (int off = 32; off; off >>= 1) v += __shfl_down(v, off, 64);
  return v;
}

// ---------------- Kernel 0: pack positions as float4 --------------------------
__global__ __launch_bounds__(256) void pack_pos4(const float* __restrict__ pos,
                                                 float4* __restrict__ pos4) {
  int g = blockIdx.x * 256 + threadIdx.x;   // 4*4096 total
  int b = g >> 12, n = g & (NPTS - 1);
  const float* pb = pos + b * 3 * NPTS;
  pos4[g] = make_float4(pb[n], pb[NPTS + n], pb[2 * NPTS + n], 0.f);
}

// ---------------- Kernel S: subset partial KNN --------------------------------
// Subset = first 256 of each 1024-quarter (1024 candidates/row), 8 chunks of 128.
__global__ __launch_bounds__(256) void knn_sub(const float4* __restrict__ pos4,
                                               uint4* __restrict__ partials) {
  __shared__ float4 cand[128];
  int t = threadIdx.x;
  int row0 = blockIdx.x * 256;
  int b = row0 >> 12;
  int y = blockIdx.y;
  int j0 = (y >> 1) * 1024 + (y & 1) * 128;
  const float4* pb = pos4 + b * NPTS;
  if (t < 128) cand[t] = pb[j0 + t];
  __syncthreads();
  float4 q = pb[(row0 + t) & (NPTS - 1)];
  unsigned dd[16];
#pragma unroll
  for (int s = 0; s < 16; ++s) dd[s] = 0xFFFFFFFFu;
#pragma unroll 4
  for (int jj = 0; jj < 128; ++jj) {
    float4 c = cand[jj];
    float dx = q.x - c.x, dy = q.y - c.y, dz = q.z - c.z;
    float d = fmaf(dx, dx, fmaf(dy, dy, dz * dz));
    unsigned key = (__float_as_uint(d) & 0xFFFFF000u) | (unsigned)(j0 + jj);
#pragma unroll
    for (int s = 0; s < 16; ++s) {
      unsigned lo = min(key, dd[s]);
      key = max(key, dd[s]);
      dd[s] = lo;
    }
  }
  uint4* po = partials + ((size_t)y * NROWS + row0 + t) * 4;
  po[0] = make_uint4(dd[0], dd[1], dd[2], dd[3]);
  po[1] = make_uint4(dd[4], dd[5], dd[6], dd[7]);
  po[2] = make_uint4(dd[8], dd[9], dd[10], dd[11]);
  po[3] = make_uint4(dd[12], dd[13], dd[14], dd[15]);
}

// ---------------- Kernel T: per-row filter threshold (LDS-staged) -------------
__global__ __launch_bounds__(64) void knn_thresh(const uint4* __restrict__ partials,
                                                 unsigned* __restrict__ T0g) {
  __shared__ unsigned sl[64 * 132];      // 33792 B
  int tid = threadIdx.x;
  int row0 = blockIdx.x * 64;
  uint4* sl4 = (uint4*)sl;
#pragma unroll
  for (int y = 0; y < 8; ++y) {
#pragma unroll
    for (int it = 0; it < 4; ++it) {
      int g = it * 64 + tid;             // 0..255 uint4s for this y
      int row = g >> 2, q = g & 3;
      sl4[row * 33 + y * 4 + q] = partials[((size_t)y * NROWS + row0 + row) * 4 + q];
    }
  }
  __syncthreads();
  unsigned top[16];
#pragma unroll
  for (int s = 0; s < 16; ++s) top[s] = 0xFFFFFFFFu;
  const unsigned* my = sl + tid * 132;
  for (int y = 0; y < 8; ++y) {
#pragma unroll 4
    for (int s = 0; s < 16; ++s) {
      unsigned key = my[y * 16 + s];
      if (key >= top[15]) break;         // chunk list sorted ascending
#pragma unroll
      for (int q2 = 0; q2 < 16; ++q2) {
        unsigned lo = min(key, top[q2]);
        key = max(key, top[q2]);
        top[q2] = lo;
      }
    }
  }
  T0g[row0 + tid] = top[15] & 0xFFFFF000u;
}

// ---------------- Kernel F: full scan, keep masked-dist <= T0 -----------------
__global__ __launch_bounds__(256) void knn_filter(const float4* __restrict__ pos4,
                                                  const unsigned* __restrict__ T0g,
                                                  unsigned* __restrict__ surv,
                                                  unsigned* __restrict__ cnts) {
  __shared__ float4 cand[512];
  int t = threadIdx.x;
  int row0 = blockIdx.x * 256;
  int b = row0 >> 12;
  int y = blockIdx.y;
  int j0 = y * 512;
  const float4* pb = pos4 + b * NPTS;
  cand[t] = pb[j0 + t];
  cand[t + 256] = pb[j0 + t + 256];
  __syncthreads();
  int r = row0 + t;
  float4 q = pb[r & (NPTS - 1)];
  unsigned T = T0g[r];
  unsigned cnt = 0;
  unsigned* my = surv + ((size_t)r * 8 + y) * 28;
#pragma unroll 4
  for (int jj = 0; jj < 512; ++jj) {
    float4 c = cand[jj];
    float dx = q.x - c.x, dy = q.y - c.y, dz = q.z - c.z;
    float d = fmaf(dx, dx, fmaf(dy, dy, dz * dz));
    unsigned m = __float_as_uint(d) & 0xFFFFF000u;
    if (m <= T) {
      if (cnt < 28u) my[cnt] = m | (unsigned)(j0 + jj);
      ++cnt;
    }
  }
  cnts[r * 8 + y] = cnt < 28u ? cnt : 28u;
}

// ---------------- Kernel M: final select — 4 lanes/row ------------------------
// 256 threads = 64 rows x 4 lanes. Lane merges its 2 chunks from LDS, then 2
// butterfly shfl_xor rounds (snapshot-then-insert) give ALL lanes the row
// top-24. Each lane redundantly f64-re-ranks (lockstep, same addrs -> L1
// broadcast), then handles 4 of 16 neighbors for gathers/stats (chain /4).
__global__ __launch_bounds__(256) void knn_final(const float4* __restrict__ pos4,
                                                 const float* __restrict__ invd,
                                                 const unsigned* __restrict__ surv,
                                                 const unsigned* __restrict__ cnts,
                                                 int* __restrict__ nn_idx,
                                                 float* __restrict__ dsbuf,
                                                 double* __restrict__ stp) {
  __shared__ unsigned sl[64 * 228];      // 58368 B
  int tid = threadIdx.x;
  int row0 = blockIdx.x * 64;
  uint4* sl4 = (uint4*)sl;
  const uint4* sg = (const uint4*)(surv + (size_t)row0 * 224);
#pragma unroll
  for (int i = 0; i < 14; ++i) {
    int g = i * 256 + tid;               // uint4 index 0..3583
    int row = g / 56, off = g % 56;      // 56 uint4 per row
    sl4[row * 57 + off] = sg[g];
  }
  __syncthreads();

  int rloc = tid >> 2;                   // local row 0..63
  int y2 = tid & 3;                      // lane within row: chunks 2*y2, 2*y2+1
  int r = row0 + rloc;
  int b = r >> 12, n = r & (NPTS - 1);

  unsigned top[24];
#pragma unroll
  for (int s = 0; s < 24; ++s) top[s] = 0xFFFFFFFFu;
  const unsigned* my = sl + rloc * 228;
  {
    unsigned ca = cnts[(size_t)r * 8 + 2 * y2];
    unsigned cb = cnts[(size_t)r * 8 + 2 * y2 + 1];
    const unsigned* pa = my + (2 * y2) * 28;
    for (unsigned i = 0; i < ca; ++i) {
      unsigned key = pa[i];
      if (key < top[23]) bub24(key, top);
    }
    const unsigned* pbx = my + (2 * y2 + 1) * 28;
    for (unsigned i = 0; i < cb; ++i) {
      unsigned key = pbx[i];
      if (key < top[23]) bub24(key, top);
    }
  }
  // butterfly: after round m=1,2 every lane holds the row's top-24
#pragma unroll
  for (int m = 1; m <= 2; m <<= 1) {
    unsigned pks[24];
#pragma unroll
    for (int s = 0; s < 24; ++s) pks[s] = (unsigned)__shfl_xor((int)top[s], m);
#pragma unroll
    for (int s = 0; s < 24; ++s) {
      unsigned key = pks[s];
      if (key < top[23]) bub24(key, top);
    }
  }

  // redundant (lockstep) exact f64 re-rank — same result on all 4 lanes
  const float4* pb = pos4 + b * NPTS;
  float4 qp = pb[n];
  double xi = qp.x, yi = qp.y, zi = qp.z;
  double dd[16]; int ii[16];
#pragma unroll
  for (int s = 0; s < 16; ++s) { dd[s] = 1e300; ii[s] = 0; }
#pragma unroll 4
  for (int s = 0; s < 24; ++s) {
    unsigned key = top[s];
    if (key != 0xFFFFFFFFu) {
      int j = (int)(key & 0xFFFu);
      float4 cj = pb[j];
      double dx = xi - (double)cj.x;
      double dy = yi - (double)cj.y;
      double dz = zi - (double)cj.z;
      double dist = dx * dx + dy * dy + dz * dz;
      if (dist < dd[15]) insert16(dist, j, dd, ii);
    }
  }

  // this lane handles neighbors s = 4*y2 .. 4*y2+3
  const float* ivb = invd + b * NPTS;
  int j0 = ii[0], j1 = ii[1], j2 = ii[2], j3 = ii[3];
  int ja, jb2, jc, jd;
  {
    // select own 4 (compile-time switch keeps everything in regs)
    int s0 = 4 * y2;
    ja = ii[0]; jb2 = ii[1]; jc = ii[2]; jd = ii[3];
    if (s0 == 4)  { ja = ii[4];  jb2 = ii[5];  jc = ii[6];  jd = ii[7];  }
    if (s0 == 8)  { ja = ii[8];  jb2 = ii[9];  jc = ii[10]; jd = ii[11]; }
    if (s0 == 12) { ja = ii[12]; jb2 = ii[13]; jc = ii[14]; jd = ii[15]; }
  }
  (void)j0; (void)j1; (void)j2; (void)j3;
  // nn_idx: one int4 store per lane
  *(int4*)(nn_idx + (size_t)r * 16 + 4 * y2) = make_int4(ja, jb2, jc, jd);
  // vmax over all 16: local max of 4, then 2-step 4-lane reduce
  float v0 = ivb[ja], v1 = ivb[jb2], v2 = ivb[jc], v3 = ivb[jd];
  float vmax = fmaxf(fmaxf(v0, v1), fmaxf(v2, v3));
  vmax = fmaxf(vmax, __shfl_xor(vmax, 1));
  vmax = fmaxf(vmax, __shfl_xor(vmax, 2));
  float x0 = v0 / vmax, x1 = v1 / vmax, x2 = v2 / vmax, x3 = v3 / vmax;
  *(float4*)(dsbuf + (size_t)r * 16 + 4 * y2) = make_float4(x0, x1, x2, x3);

  double sx = (double)x0 + x1 + x2 + x3;
  double sxx = (double)x0 * x0 + (double)x1 * x1 + (double)x2 * x2 + (double)x3 * x3;
  double l1x = 0, l1y = 0, l1z = 0;
  double lxx = 0, lyy = 0, lzz = 0, lxy = 0, lxz = 0, lyz = 0;
  {
    float4 p0 = pb[ja], p1 = pb[jb2], p2 = pb[jc], p3 = pb[jd];
#define ACC(P) { double lx = (double)P.x - xi, ly = (double)P.y - yi, lz = (double)P.z - zi; \
                 l1x += lx; l1y += ly; l1z += lz; \
                 lxx += lx * lx; lyy += ly * ly; lzz += lz * lz; \
                 lxy += lx * ly; lxz += lx * lz; lyz += ly * lz; }
    ACC(p0) ACC(p1) ACC(p2) ACC(p3)
#undef ACC
  }
  // wave-reduce (64 lanes = 16 rows x 4 lanes, all contribute) + per-wave store
  sx  = wave_reduce(sx);  sxx = wave_reduce(sxx);
  l1x = wave_reduce(l1x); l1y = wave_reduce(l1y); l1z = wave_reduce(l1z);
  lxx = wave_reduce(lxx); lyy = wave_reduce(lyy); lzz = wave_reduce(lzz);
  lxy = wave_reduce(lxy); lxz = wave_reduce(lxz); lyz = wave_reduce(lyz);
  if ((tid & 63) == 0) {
    double* o = stp + ((size_t)blockIdx.x * 4 + (tid >> 6)) * 16;
    o[0] = sx;  o[1] = sxx;
    o[2] = l1x; o[3] = l1y; o[4] = l1z;
    o[5] = lxx; o[6] = lyy; o[7] = lzz;
    o[8] = lxy; o[9] = lxz; o[10] = lyz;
  }
}

// ---------------- Kernel 3: reduce partials + fold BN into affine params ------
__global__ void finalize_params(const double* __restrict__ stp,
                                const float* __restrict__ wn_w,
                                const float* __restrict__ wn_g,
                                const float* __restrict__ wn_be,
                                const float* __restrict__ dn_w1,
                                const float* __restrict__ dn_g1,
                                const float* __restrict__ dn_be1,
                                float* __restrict__ prm) {
  __shared__ double red[11];
  const double M = (double)NROWS * 16.0;  // 262144
  int t = threadIdx.x;
  if (t < 11) {
    double s = 0.0;
#pragma unroll 8
    for (int blk = 0; blk < 1024; ++blk) s += stp[(size_t)blk * 16 + t];
    red[t] = s;
  }
  __syncthreads();
  if (t < 32) {
    double m0 = red[2] / M, m1 = red[3] / M, m2 = red[4] / M;
    double cxx = red[5] / M - m0 * m0, cyy = red[6] / M - m1 * m1, czz = red[7] / M - m2 * m2;
    double cxy = red[8] / M - m0 * m1, cxz = red[9] / M - m0 * m2, cyz = red[10] / M - m1 * m2;
    double w0 = wn_w[t * 3], w1 = wn_w[t * 3 + 1], w2 = wn_w[t * 3 + 2];
    double var = w0 * w0 * cxx + w1 * w1 * cyy + w2 * w2 * czz
               + 2.0 * (w0 * w1 * cxy + w0 * w2 * cxz + w1 * w2 * cyz);
    double alpha = (double)wn_g[t] / sqrt(var + 1e-5);
    double a0 = alpha * w0, a1 = alpha * w1, a2 = alpha * w2;
    prm[t * 3] = (float)a0; prm[t * 3 + 1] = (float)a1; prm[t * 3 + 2] = (float)a2;
    prm[96 + t] = (float)((double)wn_be[t] - (a0 * m0 + a1 * m1 + a2 * m2));
  } else if (t < 48) {
    int ch = t - 32;
    double mx = red[0] / M;
    double vx = red[1] / M - mx * mx;
    double w = dn_w1[ch];
    double alpha = (double)dn_g1[ch] * w / sqrt(w * w * vx + 1e-5);
    prm[128 + ch] = (float)alpha;
    prm[144 + ch] = (float)((double)dn_be1[ch] - alpha * mx);
  }
}

// ---------------- Kernel 5: density scale (in-place sigmoid MLP) --------------
__global__ __launch_bounds__(256) void ds_kernel(float* __restrict__ dsbuf,
                                                 const float* __restrict__ prm,
                                                 const float* __restrict__ dn_w2,
                                                 const float* __restrict__ dn_b2) {
  int r = blockIdx.x * 256 + threadIdx.x;
  float A[16], Bp[16], W2[16];
#pragma unroll
  for (int ch = 0; ch < 16; ++ch) {
    A[ch] = prm[128 + ch];
    Bp[ch] = prm[144 + ch];
    W2[ch] = dn_w2[ch];
  }
  float b2 = dn_b2[0];
#pragma unroll
  for (int k = 0; k < 16; ++k) {
    float x = dsbuf[(size_t)r * 16 + k];
    float s = b2;
#pragma unroll
    for (int ch = 0; ch < 16; ++ch) s = fmaf(W2[ch], fmaxf(fmaf(A[ch], x, Bp[ch]), 0.f), s);
    dsbuf[(size_t)r * 16 + k] = 1.f / (1.f + expf(-s));
  }
}

// ---------------- Kernel T: transpose inputs (B,C,N) f32 -> (B,N,C) bf16 ------
__global__ __launch_bounds__(256) void transpose_in(const float* __restrict__ in,
                                                    ushort* __restrict__ inT) {
  __shared__ float tile[64][68];
  int t = threadIdx.x;
  int b = blockIdx.x >> 6;
  int n0 = (blockIdx.x & 63) << 6;
  {
    int c = t >> 2, q = t & 3;
    const float* src = in + ((size_t)(b * 64 + c)) * NPTS + n0 + q * 16;
    float4 v0 = ((const float4*)src)[0];
    float4 v1 = ((const float4*)src)[1];
    float4 v2 = ((const float4*)src)[2];
    float4 v3 = ((const float4*)src)[3];
    *(float4*)&tile[c][q * 16 + 0] = v0;
    *(float4*)&tile[c][q * 16 + 4] = v1;
    *(float4*)&tile[c][q * 16 + 8] = v2;
    *(float4*)&tile[c][q * 16 + 12] = v3;
  }
  __syncthreads();
  {
    int nl = t >> 2, cq = t & 3;
    unsigned pk[8];
#pragma unroll
    for (int i = 0; i < 8; ++i) {
      float lo = tile[cq * 16 + 2 * i][nl];
      float hi = tile[cq * 16 + 2 * i + 1][nl];
      pk[i] = pk2(lo, hi);
    }
    uint4* dst = (uint4*)(inT + ((size_t)(b * NPTS + n0 + nl)) * 64 + cq * 16);
    dst[0] = make_uint4(pk[0], pk[1], pk[2], pk[3]);
    dst[1] = make_uint4(pk[4], pk[5], pk[6], pk[7]);
  }
}

// ---------------- Kernel L: pack lin_w into B-fragment order (bf16) -----------
__global__ __launch_bounds__(256) void prep_LTf(const float* __restrict__ lin_w,
                                                ushort* __restrict__ LTf) {
  int g = blockIdx.x * 256 + threadIdx.x;   // 16384
  int l = g & 63, ot = (g >> 6) & 3, s = g >> 8;
  int o = ot * 16 + (l & 15);
  const float* src = lin_w + (size_t)o * 2048 + s * 32 + (l >> 4) * 8;
  float4 u0 = ((const float4*)src)[0];
  float4 u1 = ((const float4*)src)[1];
  ((uint4*)LTf)[g] = make_uint4(pk2(u0.x, u0.y), pk2(u0.z, u0.w),
                                pk2(u1.x, u1.y), pk2(u1.z, u1.w));
}

// ------- Fused kernel: gather + WeightNet + per-point matmul + MFMA GEMM ------
#define XSTR 2320   // bytes per point: 16 k-rows * 144B (128 data + 16 pad)
#define WSTR 524    // f32 per point: 16 k * 32 w + 12 pad

#define FMA_ROW(c) \
  a##c##_0 += W0 * (f32x4)x##c; a##c##_1 += W1 * (f32x4)x##c; \
  a##c##_2 += W2 * (f32x4)x##c; a##c##_3 += W3 * (f32x4)x##c; \
  a##c##_4 += W4 * (f32x4)x##c; a##c##_5 += W5 * (f32x4)x##c; \
  a##c##_6 += W6 * (f32x4)x##c; a##c##_7 += W7 * (f32x4)x##c;

#define WRITE_C(ci, csval) \
  { size_t base = ((size_t)(csval)) * 64 + pl; \
    aq[base +  0] = make_uint4(pk2(a##ci##_0.x, a##ci##_0.y), pk2(a##ci##_0.z, a##ci##_0.w), \
                               pk2(a##ci##_1.x, a##ci##_1.y), pk2(a##ci##_1.z, a##ci##_1.w)); \
    aq[base + 16] = make_uint4(pk2(a##ci##_2.x, a##ci##_2.y), pk2(a##ci##_2.z, a##ci##_2.w), \
                               pk2(a##ci##_3.x, a##ci##_3.y), pk2(a##ci##_3.z, a##ci##_3.w)); \
    aq[base + 32] = make_uint4(pk2(a##ci##_4.x, a##ci##_4.y), pk2(a##ci##_4.z, a##ci##_4.w), \
                               pk2(a##ci##_5.x, a##ci##_5.y), pk2(a##ci##_5.z, a##ci##_5.w)); \
    aq[base + 48] = make_uint4(pk2(a##ci##_6.x, a##ci##_6.y), pk2(a##ci##_6.z, a##ci##_6.w), \
                               pk2(a##ci##_7.x, a##ci##_7.y), pk2(a##ci##_7.z, a##ci##_7.w)); }

__global__ __launch_bounds__(256, 2) void fused(const ushort* __restrict__ inT,
                                                const float4* __restrict__ pos4,
                                                const int* __restrict__ nn_idx,
                                                const float* __restrict__ dsbuf,
                                                const float* __restrict__ prm_g,
                                                const ushort* __restrict__ LTf,
                                                const float* __restrict__ lin_b,
                                                float* __restrict__ out) {
  __shared__ __align__(16) char smem[16 * XSTR + 16 * WSTR * 4];  // 70656 B
  __shared__ float prms[128];
  char* xraw = smem;
  float* wlds = (float*)(smem + 16 * XSTR);
  int t = threadIdx.x;
  int blk = blockIdx.x;          // 1024 tiles of 16 points
  int b = blk >> 8;
  int n0 = (blk & 255) << 4;
  if (t < 128) prms[t] = prm_g[t];
  __syncthreads();
  // ---- phase 1: stage. thread (k = t>>4, p = t&15) ----
  {
    int k = t >> 4, p = t & 15;
    int r = blk * 16 + p;
    int n = n0 + p;
    int j = nn_idx[(size_t)r * 16 + k];
    float4 pj = pos4[b * NPTS + j];
    float4 pn = pos4[b * NPTS + n];
    float lx = pj.x - pn.x, ly = pj.y - pn.y, lz = pj.z - pn.z;
    float ds = dsbuf[(size_t)r * 16 + k];
    const uint4* srcx = (const uint4*)(inT + ((size_t)(b * NPTS + j)) * 64);
    uint4* dstx = (uint4*)(xraw + p * XSTR + k * 144);
#pragma unroll
    for (int i = 0; i < 8; ++i) dstx[i] = srcx[i];
    float* wr = wlds + p * WSTR + k * 32;
#pragma unroll
    for (int w = 0; w < 32; ++w) {
      float v = fmaf(prms[w * 3], lx,
                fmaf(prms[w * 3 + 1], ly,
                fmaf(prms[w * 3 + 2], lz, prms[96 + w])));
      wr[w] = fmaxf(v, 0.f) * ds;
    }
  }
  __syncthreads();
  // ---- phase 2: feat in NAMED registers. thread (pl = t&15, cl = t>>4) ----
  int pl = t & 15, cl = t >> 4;
  f32x4 a0_0=(f32x4)0.f, a0_1=(f32x4)0.f, a0_2=(f32x4)0.f, a0_3=(f32x4)0.f,
        a0_4=(f32x4)0.f, a0_5=(f32x4)0.f, a0_6=(f32x4)0.f, a0_7=(f32x4)0.f;
  f32x4 a1_0=(f32x4)0.f, a1_1=(f32x4)0.f, a1_2=(f32x4)0.f, a1_3=(f32x4)0.f,
        a1_4=(f32x4)0.f, a1_5=(f32x4)0.f, a1_6=(f32x4)0.f, a1_7=(f32x4)0.f;
  f32x4 a2_0=(f32x4)0.f, a2_1=(f32x4)0.f, a2_2=(f32x4)0.f, a2_3=(f32x4)0.f,
        a2_4=(f32x4)0.f, a2_5=(f32x4)0.f, a2_6=(f32x4)0.f, a2_7=(f32x4)0.f;
  f32x4 a3_0=(f32x4)0.f, a3_1=(f32x4)0.f, a3_2=(f32x4)0.f, a3_3=(f32x4)0.f,
        a3_4=(f32x4)0.f, a3_5=(f32x4)0.f, a3_6=(f32x4)0.f, a3_7=(f32x4)0.f;
  {
    const char* xrow = xraw + pl * XSTR;
    const float* wp = wlds + pl * WSTR;
#pragma unroll 4
    for (int kk = 0; kk < 16; ++kk) {
      unsigned xa = *(const unsigned*)(xrow + kk * 144 + cl * 4);        // ch 2cl,2cl+1
      unsigned xb = *(const unsigned*)(xrow + kk * 144 + 64 + cl * 4);   // ch 32+2cl,33+2cl
      float x0 = __uint_as_float(xa << 16);
      float x1 = __uint_as_float(xa & 0xFFFF0000u);
      float x2 = __uint_as_float(xb << 16);
      float x3 = __uint_as_float(xb & 0xFFFF0000u);
      const f32x4* wk = (const f32x4*)(wp + kk * 32);
      f32x4 W0 = wk[0], W1 = wk[1], W2 = wk[2], W3 = wk[3];
      f32x4 W4 = wk[4], W5 = wk[5], W6 = wk[6], W7 = wk[7];
      FMA_ROW(0)
      FMA_ROW(1)
      FMA_ROW(2)
      FMA_ROW(3)
    }
  }
  __syncthreads();   // everyone done reading xraw/wlds
  // ---- phase 3: write A-frags (bf16) over the staging LDS (64 KB) ----
  uint4* aq = (uint4*)smem;
  WRITE_C(0, 2 * cl)
  WRITE_C(1, 2 * cl + 1)
  WRITE_C(2, 32 + 2 * cl)
  WRITE_C(3, 33 + 2 * cl)
  __syncthreads();
  // ---- phase 4: MFMA GEMM. wave wv owns output tile ot=wv, full K ----
  {
    int wv = t >> 6, l = t & 63;
    const uint4* Lq = (const uint4*)LTf;
    f32x4 cacc = (f32x4)0.f;
#pragma unroll 4
    for (int s = 0; s < 64; ++s) {
      uint4 ua = aq[s * 64 + l];
      uint4 ub = Lq[(s * 4 + wv) * 64 + l];
      bf16x8 A = *reinterpret_cast<bf16x8*>(&ua);
      bf16x8 B = *reinterpret_cast<bf16x8*>(&ub);
      cacc = __builtin_amdgcn_mfma_f32_16x16x32_bf16(A, B, cacc, 0, 0, 0);
    }
    int o = wv * 16 + (l & 15);
    float bias = lin_b[o];
    cacc.x += bias; cacc.y += bias; cacc.z += bias; cacc.w += bias;
    *(f32x4*)(out + ((size_t)(b * 64 + o)) * NPTS + n0 + (l >> 4) * 4) = cacc;
  }
}

// ------------------------------- launch ---------------------------------------
extern "C" void kernel_launch(void* const* d_in, const int* in_sizes, int n_in,
                              void* d_out, int out_size, void* d_ws, size_t ws_size,
                              hipStream_t stream) {
  (void)in_sizes; (void)n_in; (void)out_size; (void)ws_size;
  const float* inputs = (const float*)d_in[0];
  const float* pos    = (const float*)d_in[1];
  const float* invd   = (const float*)d_in[2];
  const float* wn_w   = (const float*)d_in[3];
  const float* wn_g   = (const float*)d_in[5];
  const float* wn_be  = (const float*)d_in[6];
  const float* dn_w1  = (const float*)d_in[7];
  const float* dn_g1  = (const float*)d_in[9];
  const float* dn_be1 = (const float*)d_in[10];
  const float* dn_w2  = (const float*)d_in[11];
  const float* dn_b2  = (const float*)d_in[12];
  const float* lin_w  = (const float*)d_in[13];
  const float* lin_b  = (const float*)d_in[14];
  float* outp = (float*)d_out;

  char* ws = (char*)d_ws;
  double*   stp      = (double*)(ws + 294912);                // 128 KB (1024 x 16 dbl)
  float*    prm      = (float*)(ws + 1024);                   // 640 B
  float4*   pos4     = (float4*)(ws + 4096);                  // 256 KB
  int*      nnidx    = (int*)(ws + (size_t)(1u << 19));       // 1 MB   [0.5, 1.5)
  float*    dsbuf    = (float*)(ws + (size_t)(3u << 19));     // 1 MB   [1.5, 2.5)
  ushort*   inT      = (ushort*)(ws + (size_t)(5u << 19));    // 2 MB   [2.5, 4.5)
  ushort*   LTf      = (ushort*)(ws + (size_t)(9u << 19));    // 256 KB [4.5, 4.75)
  unsigned* T0g      = (unsigned*)(ws + (size_t)(19u << 18)); // 64 KB  [4.75, ...)
  unsigned* cnts     = (unsigned*)(ws + (size_t)(19u << 18) + 65536); // 512 KB
  uint4*    partials = (uint4*)(ws + (size_t)(11u << 19));    // 8 MB   [5.5, 13.5)
  unsigned* surv     = (unsigned*)(ws + (size_t)(11u << 19)); // 14 MB  [5.5, 19.5) aliases partials

  pack_pos4<<<64, 256, 0, stream>>>(pos, pos4);
  transpose_in<<<256, 256, 0, stream>>>(inputs, inT);
  prep_LTf<<<64, 256, 0, stream>>>(lin_w, LTf);
  knn_sub<<<dim3(64, 8), 256, 0, stream>>>(pos4, partials);
  knn_thresh<<<256, 64, 0, stream>>>(partials, T0g);
  knn_filter<<<dim3(64, 8), 256, 0, stream>>>(pos4, T0g, surv, cnts);
  knn_final<<<256, 256, 0, stream>>>(pos4, invd, surv, cnts, nnidx, dsbuf, stp);
  finalize_params<<<1, 64, 0, stream>>>(stp, wn_w, wn_g, wn_be, dn_w1, dn_g1, dn_be1, prm);
  ds_kernel<<<64, 256, 0, stream>>>(dsbuf, prm, dn_w2, dn_b2);
  fused<<<1024, 256, 0, stream>>>(inT, pos4, nnidx, dsbuf, prm, LTf, lin_b, outp);
}

// Round 14
// 188.256 us; speedup vs baseline: 1.1301x; 1.1301x over previous
//
#include <hip/hip_runtime.h>
#include <math.h>

// Problem constants
#define NB 4
#define NC 64
#define NPTS 4096
#define NROWS (NB*NPTS)      // 16384

typedef __attribute__((ext_vector_type(4))) float f32x4;
typedef __bf16 bf16x8 __attribute__((ext_vector_type(8)));

__device__ __forceinline__ ushort f2bf(float f) {
  unsigned u = __float_as_uint(f);
  u = (u + 0x7FFFu + ((u >> 16) & 1u)) >> 16;   // RNE
  return (ushort)u;
}
__device__ __forceinline__ unsigned pk2(float lo, float hi) {
  return (unsigned)f2bf(lo) | ((unsigned)f2bf(hi) << 16);
}

// ---------------- top-16 insertion (sorted ascending, dd[15]=max) -------------
__device__ __forceinline__ void insert16(double dist, int j, double (&dd)[16], int (&ii)[16]) {
  double cd = dist; int ci = j;
#pragma unroll
  for (int s = 0; s < 16; ++s) {
    double od = dd[s]; int oi = ii[s];
    bool c = cd < od;
    dd[s] = c ? cd : od;
    ii[s] = c ? ci : oi;
    cd = c ? od : cd;
    ci = c ? oi : ci;
  }
}

__device__ __forceinline__ void bub24(unsigned key, unsigned (&top)[24]) {
#pragma unroll
  for (int q2 = 0; q2 < 24; ++q2) {
    unsigned lo = min(key, top[q2]);
    key = max(key, top[q2]);
    top[q2] = lo;
  }
}

__device__ __forceinline__ double wave_reduce(double v) {
#pragma unroll
  for (int off = 32; off; off >>= 1) v += __shfl_down(v, off, 64);
  return v;
}

// ---------------- Kernel 0: pack positions as float4 --------------------------
__global__ __launch_bounds__(256) void pack_pos4(const float* __restrict__ pos,
                                                 float4* __restrict__ pos4) {
  int g = blockIdx.x * 256 + threadIdx.x;   // 4*4096 total
  int b = g >> 12, n = g & (NPTS - 1);
  const float* pb = pos + b * 3 * NPTS;
  pos4[g] = make_float4(pb[n], pb[NPTS + n], pb[2 * NPTS + n], 0.f);
}

// ---------------- Kernel S: subset partial KNN --------------------------------
// Subset = first 256 of each 1024-quarter (1024 candidates/row), 8 chunks of 128.
__global__ __launch_bounds__(256) void knn_sub(const float4* __restrict__ pos4,
                                               uint4* __restrict__ partials) {
  __shared__ float4 cand[128];
  int t = threadIdx.x;
  int row0 = blockIdx.x * 256;
  int b = row0 >> 12;
  int y = blockIdx.y;
  int j0 = (y >> 1) * 1024 + (y & 1) * 128;
  const float4* pb = pos4 + b * NPTS;
  if (t < 128) cand[t] = pb[j0 + t];
  __syncthreads();
  float4 q = pb[(row0 + t) & (NPTS - 1)];
  unsigned dd[16];
#pragma unroll
  for (int s = 0; s < 16; ++s) dd[s] = 0xFFFFFFFFu;
#pragma unroll 4
  for (int jj = 0; jj < 128; ++jj) {
    float4 c = cand[jj];
    float dx = q.x - c.x, dy = q.y - c.y, dz = q.z - c.z;
    float d = fmaf(dx, dx, fmaf(dy, dy, dz * dz));
    unsigned key = (__float_as_uint(d) & 0xFFFFF000u) | (unsigned)(j0 + jj);
#pragma unroll
    for (int s = 0; s < 16; ++s) {
      unsigned lo = min(key, dd[s]);
      key = max(key, dd[s]);
      dd[s] = lo;
    }
  }
  uint4* po = partials + ((size_t)y * NROWS + row0 + t) * 4;
  po[0] = make_uint4(dd[0], dd[1], dd[2], dd[3]);
  po[1] = make_uint4(dd[4], dd[5], dd[6], dd[7]);
  po[2] = make_uint4(dd[8], dd[9], dd[10], dd[11]);
  po[3] = make_uint4(dd[12], dd[13], dd[14], dd[15]);
}

// ---------------- Kernel T: per-row filter threshold (batched LDS staging) ----
__global__ __launch_bounds__(64) void knn_thresh(const uint4* __restrict__ partials,
                                                 unsigned* __restrict__ T0g) {
  __shared__ unsigned sl[64 * 132];      // 33792 B
  int tid = threadIdx.x;
  int row0 = blockIdx.x * 64;
  uint4* sl4 = (uint4*)sl;
  size_t base = (size_t)row0 * 4 + tid;
#define TW(IT, V) { int g2 = ((IT) & 3) * 64 + tid; \
                    sl4[(g2 >> 2) * 33 + ((IT) >> 2) * 4 + (g2 & 3)] = (V); }
#define TB(B) { int IT0 = (B) * 8; \
  uint4 w0 = partials[(size_t)((IT0+0)>>2)*(NROWS*4) + ((IT0+0)&3)*64 + base]; \
  uint4 w1 = partials[(size_t)((IT0+1)>>2)*(NROWS*4) + ((IT0+1)&3)*64 + base]; \
  uint4 w2 = partials[(size_t)((IT0+2)>>2)*(NROWS*4) + ((IT0+2)&3)*64 + base]; \
  uint4 w3 = partials[(size_t)((IT0+3)>>2)*(NROWS*4) + ((IT0+3)&3)*64 + base]; \
  uint4 w4 = partials[(size_t)((IT0+4)>>2)*(NROWS*4) + ((IT0+4)&3)*64 + base]; \
  uint4 w5 = partials[(size_t)((IT0+5)>>2)*(NROWS*4) + ((IT0+5)&3)*64 + base]; \
  uint4 w6 = partials[(size_t)((IT0+6)>>2)*(NROWS*4) + ((IT0+6)&3)*64 + base]; \
  uint4 w7 = partials[(size_t)((IT0+7)>>2)*(NROWS*4) + ((IT0+7)&3)*64 + base]; \
  TW(IT0+0,w0) TW(IT0+1,w1) TW(IT0+2,w2) TW(IT0+3,w3) \
  TW(IT0+4,w4) TW(IT0+5,w5) TW(IT0+6,w6) TW(IT0+7,w7) }
  TB(0) TB(1) TB(2) TB(3)
#undef TB
#undef TW
  __syncthreads();
  unsigned top[16];
#pragma unroll
  for (int s = 0; s < 16; ++s) top[s] = 0xFFFFFFFFu;
  const unsigned* my = sl + tid * 132;
  for (int y = 0; y < 8; ++y) {
#pragma unroll 4
    for (int s = 0; s < 16; ++s) {
      unsigned key = my[y * 16 + s];
      if (key >= top[15]) break;         // chunk list sorted ascending
#pragma unroll
      for (int q2 = 0; q2 < 16; ++q2) {
        unsigned lo = min(key, top[q2]);
        key = max(key, top[q2]);
        top[q2] = lo;
      }
    }
  }
  T0g[row0 + tid] = top[15] & 0xFFFFF000u;
}

// ---------------- Kernel F: full scan, LDS survivor queues --------------------
// Conditional body = 2-op ds_write; copy-out = 7 vectorized uint4 stores.
__global__ __launch_bounds__(256) void knn_filter(const float4* __restrict__ pos4,
                                                  const unsigned* __restrict__ T0g,
                                                  unsigned* __restrict__ surv,
                                                  unsigned* __restrict__ cnts) {
  __shared__ float4 cand[512];
  __shared__ unsigned lq[256 * 28];      // 28 KB, stride 112B (16B aligned)
  int t = threadIdx.x;
  int row0 = blockIdx.x * 256;
  int b = row0 >> 12;
  int y = blockIdx.y;
  int j0 = y * 512;
  const float4* pb = pos4 + b * NPTS;
  cand[t] = pb[j0 + t];
  cand[t + 256] = pb[j0 + t + 256];
  __syncthreads();
  int r = row0 + t;
  float4 q = pb[r & (NPTS - 1)];
  unsigned T = T0g[r];
  unsigned cnt = 0;
  unsigned* myq = lq + t * 28;
#pragma unroll 4
  for (int jj = 0; jj < 512; ++jj) {
    float4 c = cand[jj];
    float dx = q.x - c.x, dy = q.y - c.y, dz = q.z - c.z;
    float d = fmaf(dx, dx, fmaf(dy, dy, dz * dz));
    unsigned m = __float_as_uint(d) & 0xFFFFF000u;
    if (m <= T) {
      if (cnt < 28u) myq[cnt] = m | (unsigned)(j0 + jj);
      ++cnt;
    }
  }
  cnt = cnt < 28u ? cnt : 28u;
  cnts[r * 8 + y] = cnt;
  uint4* dst = (uint4*)(surv + ((size_t)r * 8 + y) * 28);
  const uint4* src = (const uint4*)myq;
#pragma unroll
  for (int i = 0; i < 7; ++i) dst[i] = src[i];
}

// ---------------- Kernel M: final select (batched staging), rerank, stats -----
// r12-proven select structure; staging via 8-wide named-register batches.
__global__ __launch_bounds__(64) void knn_final(const float4* __restrict__ pos4,
                                                const float* __restrict__ invd,
                                                const unsigned* __restrict__ surv,
                                                const unsigned* __restrict__ cnts,
                                                int* __restrict__ nn_idx,
                                                float* __restrict__ dsbuf,
                                                double* __restrict__ stp) {
  __shared__ unsigned sl[64 * 228];      // 58368 B
  int tid = threadIdx.x;
  int row0 = blockIdx.x * 64;
  uint4* sl4 = (uint4*)sl;
  const uint4* sg = (const uint4*)(surv + (size_t)row0 * 224);
  int r = row0 + tid;
  const uint4* cp = (const uint4*)(cnts + (size_t)r * 8);
  uint4 c0 = cp[0], c1 = cp[1];          // hoisted, issues with staging
#define STW(G, V) { int rw = (G) / 56, of = (G) % 56; sl4[rw * 57 + of] = (V); }
#define LDB(B) { int g0 = (B) * 512 + tid; \
  uint4 v0 = sg[g0], v1 = sg[g0 + 64], v2 = sg[g0 + 128], v3 = sg[g0 + 192], \
        v4 = sg[g0 + 256], v5 = sg[g0 + 320], v6 = sg[g0 + 384], v7 = sg[g0 + 448]; \
  STW(g0, v0) STW(g0 + 64, v1) STW(g0 + 128, v2) STW(g0 + 192, v3) \
  STW(g0 + 256, v4) STW(g0 + 320, v5) STW(g0 + 384, v6) STW(g0 + 448, v7) }
  LDB(0) LDB(1) LDB(2) LDB(3) LDB(4) LDB(5) LDB(6)
#undef LDB
#undef STW
  __syncthreads();

  int b = r >> 12, n = r & (NPTS - 1);

  unsigned top[24];
#pragma unroll
  for (int s = 0; s < 24; ++s) top[s] = 0xFFFFFFFFu;
  const unsigned* my = sl + tid * 228;
#define MCH(YY, CC) { const unsigned* py = my + (YY) * 28; unsigned cc = (CC); \
  for (unsigned i = 0; i < cc; ++i) { unsigned key = py[i]; \
    if (key < top[23]) bub24(key, top); } }
  MCH(0, c0.x) MCH(1, c0.y) MCH(2, c0.z) MCH(3, c0.w)
  MCH(4, c1.x) MCH(5, c1.y) MCH(6, c1.z) MCH(7, c1.w)
#undef MCH

  // exact f64 re-rank of top-24 survivors — matches numpy-f64
  const float4* pb = pos4 + b * NPTS;
  float4 qp = pb[n];
  double xi = qp.x, yi = qp.y, zi = qp.z;
  double dd[16]; int ii[16];
#pragma unroll
  for (int s = 0; s < 16; ++s) { dd[s] = 1e300; ii[s] = 0; }
#pragma unroll 4
  for (int s = 0; s < 24; ++s) {
    unsigned key = top[s];
    if (key != 0xFFFFFFFFu) {
      int j = (int)(key & 0xFFFu);
      float4 cj = pb[j];
      double dx = xi - (double)cj.x;
      double dy = yi - (double)cj.y;
      double dz = zi - (double)cj.z;
      double dist = dx * dx + dy * dy + dz * dz;
      if (dist < dd[15]) insert16(dist, j, dd, ii);
    }
  }

  const float* ivb = invd + b * NPTS;
  float xv[16];
  float vmax = -1e30f;
#pragma unroll
  for (int s = 0; s < 16; ++s) {
    int j = ii[s];
    nn_idx[(size_t)r * 16 + s] = j;
    float v = ivb[j];
    xv[s] = v;
    vmax = fmaxf(vmax, v);
  }
  double sx = 0, sxx = 0;
  double l1x = 0, l1y = 0, l1z = 0;
  double lxx = 0, lyy = 0, lzz = 0, lxy = 0, lxz = 0, lyz = 0;
#pragma unroll
  for (int s = 0; s < 16; ++s) {
    float x = xv[s] / vmax;
    dsbuf[(size_t)r * 16 + s] = x;
    sx += x; sxx += (double)x * (double)x;
    int j = ii[s];
    float4 cj = pb[j];
    double lx = (double)cj.x - xi;
    double ly = (double)cj.y - yi;
    double lz = (double)cj.z - zi;
    l1x += lx; l1y += ly; l1z += lz;
    lxx += lx * lx; lyy += ly * ly; lzz += lz * lz;
    lxy += lx * ly; lxz += lx * lz; lyz += ly * lz;
  }
  sx  = wave_reduce(sx);  sxx = wave_reduce(sxx);
  l1x = wave_reduce(l1x); l1y = wave_reduce(l1y); l1z = wave_reduce(l1z);
  lxx = wave_reduce(lxx); lyy = wave_reduce(lyy); lzz = wave_reduce(lzz);
  lxy = wave_reduce(lxy); lxz = wave_reduce(lxz); lyz = wave_reduce(lyz);
  if (tid == 0) {
    double* o = stp + (size_t)blockIdx.x * 16;
    o[0] = sx;  o[1] = sxx;
    o[2] = l1x; o[3] = l1y; o[4] = l1z;
    o[5] = lxx; o[6] = lyy; o[7] = lzz;
    o[8] = lxy; o[9] = lxz; o[10] = lyz;
  }
}

// ---------------- Kernel 3: reduce partials + fold BN into affine params ------
__global__ void finalize_params(const double* __restrict__ stp,
                                const float* __restrict__ wn_w,
                                const float* __restrict__ wn_g,
                                const float* __restrict__ wn_be,
                                const float* __restrict__ dn_w1,
                                const float* __restrict__ dn_g1,
                                const float* __restrict__ dn_be1,
                                float* __restrict__ prm) {
  __shared__ double red[11];
  const double M = (double)NROWS * 16.0;  // 262144
  int t = threadIdx.x;
  if (t < 11) {
    double s = 0.0;
#pragma unroll 8
    for (int blk = 0; blk < 256; ++blk) s += stp[(size_t)blk * 16 + t];
    red[t] = s;
  }
  __syncthreads();
  if (t < 32) {
    double m0 = red[2] / M, m1 = red[3] / M, m2 = red[4] / M;
    double cxx = red[5] / M - m0 * m0, cyy = red[6] / M - m1 * m1, czz = red[7] / M - m2 * m2;
    double cxy = red[8] / M - m0 * m1, cxz = red[9] / M - m0 * m2, cyz = red[10] / M - m1 * m2;
    double w0 = wn_w[t * 3], w1 = wn_w[t * 3 + 1], w2 = wn_w[t * 3 + 2];
    double var = w0 * w0 * cxx + w1 * w1 * cyy + w2 * w2 * czz
               + 2.0 * (w0 * w1 * cxy + w0 * w2 * cxz + w1 * w2 * cyz);
    double alpha = (double)wn_g[t] / sqrt(var + 1e-5);
    double a0 = alpha * w0, a1 = alpha * w1, a2 = alpha * w2;
    prm[t * 3] = (float)a0; prm[t * 3 + 1] = (float)a1; prm[t * 3 + 2] = (float)a2;
    prm[96 + t] = (float)((double)wn_be[t] - (a0 * m0 + a1 * m1 + a2 * m2));
  } else if (t < 48) {
    int ch = t - 32;
    double mx = red[0] / M;
    double vx = red[1] / M - mx * mx;
    double w = dn_w1[ch];
    double alpha = (double)dn_g1[ch] * w / sqrt(w * w * vx + 1e-5);
    prm[128 + ch] = (float)alpha;
    prm[144 + ch] = (float)((double)dn_be1[ch] - alpha * mx);
  }
}

// ---------------- Kernel 5: density scale (in-place sigmoid MLP) --------------
__global__ __launch_bounds__(256) void ds_kernel(float* __restrict__ dsbuf,
                                                 const float* __restrict__ prm,
                                                 const float* __restrict__ dn_w2,
                                                 const float* __restrict__ dn_b2) {
  int r = blockIdx.x * 256 + threadIdx.x;
  float A[16], Bp[16], W2[16];
#pragma unroll
  for (int ch = 0; ch < 16; ++ch) {
    A[ch] = prm[128 + ch];
    Bp[ch] = prm[144 + ch];
    W2[ch] = dn_w2[ch];
  }
  float b2 = dn_b2[0];
#pragma unroll
  for (int k = 0; k < 16; ++k) {
    float x = dsbuf[(size_t)r * 16 + k];
    float s = b2;
#pragma unroll
    for (int ch = 0; ch < 16; ++ch) s = fmaf(W2[ch], fmaxf(fmaf(A[ch], x, Bp[ch]), 0.f), s);
    dsbuf[(size_t)r * 16 + k] = 1.f / (1.f + expf(-s));
  }
}

// ---------------- Kernel T: transpose inputs (B,C,N) f32 -> (B,N,C) bf16 ------
__global__ __launch_bounds__(256) void transpose_in(const float* __restrict__ in,
                                                    ushort* __restrict__ inT) {
  __shared__ float tile[64][68];
  int t = threadIdx.x;
  int b = blockIdx.x >> 6;
  int n0 = (blockIdx.x & 63) << 6;
  {
    int c = t >> 2, q = t & 3;
    const float* src = in + ((size_t)(b * 64 + c)) * NPTS + n0 + q * 16;
    float4 v0 = ((const float4*)src)[0];
    float4 v1 = ((const float4*)src)[1];
    float4 v2 = ((const float4*)src)[2];
    float4 v3 = ((const float4*)src)[3];
    *(float4*)&tile[c][q * 16 + 0] = v0;
    *(float4*)&tile[c][q * 16 + 4] = v1;
    *(float4*)&tile[c][q * 16 + 8] = v2;
    *(float4*)&tile[c][q * 16 + 12] = v3;
  }
  __syncthreads();
  {
    int nl = t >> 2, cq = t & 3;
    unsigned pk[8];
#pragma unroll
    for (int i = 0; i < 8; ++i) {
      float lo = tile[cq * 16 + 2 * i][nl];
      float hi = tile[cq * 16 + 2 * i + 1][nl];
      pk[i] = pk2(lo, hi);
    }
    uint4* dst = (uint4*)(inT + ((size_t)(b * NPTS + n0 + nl)) * 64 + cq * 16);
    dst[0] = make_uint4(pk[0], pk[1], pk[2], pk[3]);
    dst[1] = make_uint4(pk[4], pk[5], pk[6], pk[7]);
  }
}

// ---------------- Kernel L: pack lin_w into B-fragment order (bf16) -----------
__global__ __launch_bounds__(256) void prep_LTf(const float* __restrict__ lin_w,
                                                ushort* __restrict__ LTf) {
  int g = blockIdx.x * 256 + threadIdx.x;   // 16384
  int l = g & 63, ot = (g >> 6) & 3, s = g >> 8;
  int o = ot * 16 + (l & 15);
  const float* src = lin_w + (size_t)o * 2048 + s * 32 + (l >> 4) * 8;
  float4 u0 = ((const float4*)src)[0];
  float4 u1 = ((const float4*)src)[1];
  ((uint4*)LTf)[g] = make_uint4(pk2(u0.x, u0.y), pk2(u0.z, u0.w),
                                pk2(u1.x, u1.y), pk2(u1.z, u1.w));
}

// ------- Fused kernel: gather + WeightNet + per-point matmul + MFMA GEMM ------
#define XSTR 2320   // bytes per point: 16 k-rows * 144B (128 data + 16 pad)
#define WSTR 524    // f32 per point: 16 k * 32 w + 12 pad

#define FMA_ROW(c) \
  a##c##_0 += W0 * (f32x4)x##c; a##c##_1 += W1 * (f32x4)x##c; \
  a##c##_2 += W2 * (f32x4)x##c; a##c##_3 += W3 * (f32x4)x##c; \
  a##c##_4 += W4 * (f32x4)x##c; a##c##_5 += W5 * (f32x4)x##c; \
  a##c##_6 += W6 * (f32x4)x##c; a##c##_7 += W7 * (f32x4)x##c;

#define WRITE_C(ci, csval) \
  { size_t base = ((size_t)(csval)) * 64 + pl; \
    aq[base +  0] = make_uint4(pk2(a##ci##_0.x, a##ci##_0.y), pk2(a##ci##_0.z, a##ci##_0.w), \
                               pk2(a##ci##_1.x, a##ci##_1.y), pk2(a##ci##_1.z, a##ci##_1.w)); \
    aq[base + 16] = make_uint4(pk2(a##ci##_2.x, a##ci##_2.y), pk2(a##ci##_2.z, a##ci##_2.w), \
                               pk2(a##ci##_3.x, a##ci##_3.y), pk2(a##ci##_3.z, a##ci##_3.w)); \
    aq[base + 32] = make_uint4(pk2(a##ci##_4.x, a##ci##_4.y), pk2(a##ci##_4.z, a##ci##_4.w), \
                               pk2(a##ci##_5.x, a##ci##_5.y), pk2(a##ci##_5.z, a##ci##_5.w)); \
    aq[base + 48] = make_uint4(pk2(a##ci##_6.x, a##ci##_6.y), pk2(a##ci##_6.z, a##ci##_6.w), \
                               pk2(a##ci##_7.x, a##ci##_7.y), pk2(a##ci##_7.z, a##ci##_7.w)); }

__global__ __launch_bounds__(256, 2) void fused(const ushort* __restrict__ inT,
                                                const float4* __restrict__ pos4,
                                                const int* __restrict__ nn_idx,
                                                const float* __restrict__ dsbuf,
                                                const float* __restrict__ prm_g,
                                                const ushort* __restrict__ LTf,
                                                const float* __restrict__ lin_b,
                                                float* __restrict__ out) {
  __shared__ __align__(16) char smem[16 * XSTR + 16 * WSTR * 4];  // 70656 B
  __shared__ float prms[128];
  char* xraw = smem;
  float* wlds = (float*)(smem + 16 * XSTR);
  int t = threadIdx.x;
  int blk = blockIdx.x;          // 1024 tiles of 16 points
  int b = blk >> 8;
  int n0 = (blk & 255) << 4;
  if (t < 128) prms[t] = prm_g[t];
  __syncthreads();
  // ---- phase 1: stage. thread (k = t>>4, p = t&15) ----
  {
    int k = t >> 4, p = t & 15;
    int r = blk * 16 + p;
    int n = n0 + p;
    int j = nn_idx[(size_t)r * 16 + k];
    float4 pj = pos4[b * NPTS + j];
    float4 pn = pos4[b * NPTS + n];
    float lx = pj.x - pn.x, ly = pj.y - pn.y, lz = pj.z - pn.z;
    float ds = dsbuf[(size_t)r * 16 + k];
    const uint4* srcx = (const uint4*)(inT + ((size_t)(b * NPTS + j)) * 64);
    uint4* dstx = (uint4*)(xraw + p * XSTR + k * 144);
#pragma unroll
    for (int i = 0; i < 8; ++i) dstx[i] = srcx[i];
    float* wr = wlds + p * WSTR + k * 32;
#pragma unroll
    for (int w = 0; w < 32; ++w) {
      float v = fmaf(prms[w * 3], lx,
                fmaf(prms[w * 3 + 1], ly,
                fmaf(prms[w * 3 + 2], lz, prms[96 + w])));
      wr[w] = fmaxf(v, 0.f) * ds;
    }
  }
  __syncthreads();
  // ---- phase 2: feat in NAMED registers. thread (pl = t&15, cl = t>>4) ----
  int pl = t & 15, cl = t >> 4;
  f32x4 a0_0=(f32x4)0.f, a0_1=(f32x4)0.f, a0_2=(f32x4)0.f, a0_3=(f32x4)0.f,
        a0_4=(f32x4)0.f, a0_5=(f32x4)0.f, a0_6=(f32x4)0.f, a0_7=(f32x4)0.f;
  f32x4 a1_0=(f32x4)0.f, a1_1=(f32x4)0.f, a1_2=(f32x4)0.f, a1_3=(f32x4)0.f,
        a1_4=(f32x4)0.f, a1_5=(f32x4)0.f, a1_6=(f32x4)0.f, a1_7=(f32x4)0.f;
  f32x4 a2_0=(f32x4)0.f, a2_1=(f32x4)0.f, a2_2=(f32x4)0.f, a2_3=(f32x4)0.f,
        a2_4=(f32x4)0.f, a2_5=(f32x4)0.f, a2_6=(f32x4)0.f, a2_7=(f32x4)0.f;
  f32x4 a3_0=(f32x4)0.f, a3_1=(f32x4)0.f, a3_2=(f32x4)0.f, a3_3=(f32x4)0.f,
        a3_4=(f32x4)0.f, a3_5=(f32x4)0.f, a3_6=(f32x4)0.f, a3_7=(f32x4)0.f;
  {
    const char* xrow = xraw + pl * XSTR;
    const float* wp = wlds + pl * WSTR;
#pragma unroll 4
    for (int kk = 0; kk < 16; ++kk) {
      unsigned xa = *(const unsigned*)(xrow + kk * 144 + cl * 4);        // ch 2cl,2cl+1
      unsigned xb = *(const unsigned*)(xrow + kk * 144 + 64 + cl * 4);   // ch 32+2cl,33+2cl
      float x0 = __uint_as_float(xa << 16);
      float x1 = __uint_as_float(xa & 0xFFFF0000u);
      float x2 = __uint_as_float(xb << 16);
      float x3 = __uint_as_float(xb & 0xFFFF0000u);
      const f32x4* wk = (const f32x4*)(wp + kk * 32);
      f32x4 W0 = wk[0], W1 = wk[1], W2 = wk[2], W3 = wk[3];
      f32x4 W4 = wk[4], W5 = wk[5], W6 = wk[6], W7 = wk[7];
      FMA_ROW(0)
      FMA_ROW(1)
      FMA_ROW(2)
      FMA_ROW(3)
    }
  }
  __syncthreads();   // everyone done reading xraw/wlds
  // ---- phase 3: write A-frags (bf16) over the staging LDS (64 KB) ----
  uint4* aq = (uint4*)smem;
  WRITE_C(0, 2 * cl)
  WRITE_C(1, 2 * cl + 1)
  WRITE_C(2, 32 + 2 * cl)
  WRITE_C(3, 33 + 2 * cl)
  __syncthreads();
  // ---- phase 4: MFMA GEMM. wave wv owns output tile ot=wv, full K ----
  {
    int wv = t >> 6, l = t & 63;
    const uint4* Lq = (const uint4*)LTf;
    f32x4 cacc = (f32x4)0.f;
#pragma unroll 4
    for (int s = 0; s < 64; ++s) {
      uint4 ua = aq[s * 64 + l];
      uint4 ub = Lq[(s * 4 + wv) * 64 + l];
      bf16x8 A = *reinterpret_cast<bf16x8*>(&ua);
      bf16x8 B = *reinterpret_cast<bf16x8*>(&ub);
      cacc = __builtin_amdgcn_mfma_f32_16x16x32_bf16(A, B, cacc, 0, 0, 0);
    }
    int o = wv * 16 + (l & 15);
    float bias = lin_b[o];
    cacc.x += bias; cacc.y += bias; cacc.z += bias; cacc.w += bias;
    *(f32x4*)(out + ((size_t)(b * 64 + o)) * NPTS + n0 + (l >> 4) * 4) = cacc;
  }
}

// ------------------------------- launch ---------------------------------------
extern "C" void kernel_launch(void* const* d_in, const int* in_sizes, int n_in,
                              void* d_out, int out_size, void* d_ws, size_t ws_size,
                              hipStream_t stream) {
  (void)in_sizes; (void)n_in; (void)out_size; (void)ws_size;
  const float* inputs = (const float*)d_in[0];
  const float* pos    = (const float*)d_in[1];
  const float* invd   = (const float*)d_in[2];
  const float* wn_w   = (const float*)d_in[3];
  const float* wn_g   = (const float*)d_in[5];
  const float* wn_be  = (const float*)d_in[6];
  const float* dn_w1  = (const float*)d_in[7];
  const float* dn_g1  = (const float*)d_in[9];
  const float* dn_be1 = (const float*)d_in[10];
  const float* dn_w2  = (const float*)d_in[11];
  const float* dn_b2  = (const float*)d_in[12];
  const float* lin_w  = (const float*)d_in[13];
  const float* lin_b  = (const float*)d_in[14];
  float* outp = (float*)d_out;

  char* ws = (char*)d_ws;
  double*   stp      = (double*)(ws + 294912);                // 32 KB  (256 x 16 dbl)
  float*    prm      = (float*)(ws + 1024);                   // 640 B
  float4*   pos4     = (float4*)(ws + 4096);                  // 256 KB
  int*      nnidx    = (int*)(ws + (size_t)(1u << 19));       // 1 MB   [0.5, 1.5)
  float*    dsbuf    = (float*)(ws + (size_t)(3u << 19));     // 1 MB   [1.5, 2.5)
  ushort*   inT      = (ushort*)(ws + (size_t)(5u << 19));    // 2 MB   [2.5, 4.5)
  ushort*   LTf      = (ushort*)(ws + (size_t)(9u << 19));    // 256 KB [4.5, 4.75)
  unsigned* T0g      = (unsigned*)(ws + (size_t)(19u << 18)); // 64 KB  [4.75, ...)
  unsigned* cnts     = (unsigned*)(ws + (size_t)(19u << 18) + 65536); // 512 KB
  uint4*    partials = (uint4*)(ws + (size_t)(11u << 19));    // 8 MB   [5.5, 13.5)
  unsigned* surv     = (unsigned*)(ws + (size_t)(11u << 19)); // 14 MB  [5.5, 19.5) aliases partials

  pack_pos4<<<64, 256, 0, stream>>>(pos, pos4);
  transpose_in<<<256, 256, 0, stream>>>(inputs, inT);
  prep_LTf<<<64, 256, 0, stream>>>(lin_w, LTf);
  knn_sub<<<dim3(64, 8), 256, 0, stream>>>(pos4, partials);
  knn_thresh<<<256, 64, 0, stream>>>(partials, T0g);
  knn_filter<<<dim3(64, 8), 256, 0, stream>>>(pos4, T0g, surv, cnts);
  knn_final<<<256, 64, 0, stream>>>(pos4, invd, surv, cnts, nnidx, dsbuf, stp);
  finalize_params<<<1, 64, 0, stream>>>(stp, wn_w, wn_g, wn_be, dn_w1, dn_g1, dn_be1, prm);
  ds_kernel<<<64, 256, 0, stream>>>(dsbuf, prm, dn_w2, dn_b2);
  fused<<<1024, 256, 0, stream>>>(inT, pos4, nnidx, dsbuf, prm, LTf, lin_b, outp);
}

// Round 15
// 177.476 us; speedup vs baseline: 1.1988x; 1.0607x over previous
//
#include <hip/hip_runtime.h>
#include <math.h>

// Problem constants
#define NB 4
#define NC 64
#define NPTS 4096
#define NROWS (NB*NPTS)      // 16384

typedef __attribute__((ext_vector_type(4))) float f32x4;
typedef __bf16 bf16x8 __attribute__((ext_vector_type(8)));

__device__ __forceinline__ ushort f2bf(float f) {
  unsigned u = __float_as_uint(f);
  u = (u + 0x7FFFu + ((u >> 16) & 1u)) >> 16;   // RNE
  return (ushort)u;
}
__device__ __forceinline__ unsigned pk2(float lo, float hi) {
  return (unsigned)f2bf(lo) | ((unsigned)f2bf(hi) << 16);
}

// ---------------- top-16 insertion (sorted ascending, dd[15]=max) -------------
__device__ __forceinline__ void insert16(double dist, int j, double (&dd)[16], int (&ii)[16]) {
  double cd = dist; int ci = j;
#pragma unroll
  for (int s = 0; s < 16; ++s) {
    double od = dd[s]; int oi = ii[s];
    bool c = cd < od;
    dd[s] = c ? cd : od;
    ii[s] = c ? ci : oi;
    cd = c ? od : cd;
    ci = c ? oi : ci;
  }
}

__device__ __forceinline__ void bub24(unsigned key, unsigned (&top)[24]) {
#pragma unroll
  for (int q2 = 0; q2 < 24; ++q2) {
    unsigned lo = min(key, top[q2]);
    key = max(key, top[q2]);
    top[q2] = lo;
  }
}

__device__ __forceinline__ void bub16u(unsigned key, unsigned (&t)[16]) {
#pragma unroll
  for (int q2 = 0; q2 < 16; ++q2) {
    unsigned lo = min(key, t[q2]);
    key = max(key, t[q2]);
    t[q2] = lo;
  }
}

__device__ __forceinline__ double wave_reduce(double v) {
#pragma unroll
  for (int off = 32; off; off >>= 1) v += __shfl_down(v, off, 64);
  return v;
}

// ---------------- Kernel 0: pack positions as float4 --------------------------
__global__ __launch_bounds__(256) void pack_pos4(const float* __restrict__ pos,
                                                 float4* __restrict__ pos4) {
  int g = blockIdx.x * 256 + threadIdx.x;   // 4*4096 total
  int b = g >> 12, n = g & (NPTS - 1);
  const float* pb = pos + b * 3 * NPTS;
  pos4[g] = make_float4(pb[n], pb[NPTS + n], pb[2 * NPTS + n], 0.f);
}

// ---------------- Kernel S: subset partial KNN --------------------------------
// Subset = first 256 of each 1024-quarter (1024 candidates/row), 8 chunks of 128.
__global__ __launch_bounds__(256) void knn_sub(const float4* __restrict__ pos4,
                                               uint4* __restrict__ partials) {
  __shared__ float4 cand[128];
  int t = threadIdx.x;
  int row0 = blockIdx.x * 256;
  int b = row0 >> 12;
  int y = blockIdx.y;
  int j0 = (y >> 1) * 1024 + (y & 1) * 128;
  const float4* pb = pos4 + b * NPTS;
  if (t < 128) cand[t] = pb[j0 + t];
  __syncthreads();
  float4 q = pb[(row0 + t) & (NPTS - 1)];
  unsigned dd[16];
#pragma unroll
  for (int s = 0; s < 16; ++s) dd[s] = 0xFFFFFFFFu;
#pragma unroll 4
  for (int jj = 0; jj < 128; ++jj) {
    float4 c = cand[jj];
    float dx = q.x - c.x, dy = q.y - c.y, dz = q.z - c.z;
    float d = fmaf(dx, dx, fmaf(dy, dy, dz * dz));
    unsigned key = (__float_as_uint(d) & 0xFFFFF000u) | (unsigned)(j0 + jj);
#pragma unroll
    for (int s = 0; s < 16; ++s) {
      unsigned lo = min(key, dd[s]);
      key = max(key, dd[s]);
      dd[s] = lo;
    }
  }
  uint4* po = partials + ((size_t)y * NROWS + row0 + t) * 4;
  po[0] = make_uint4(dd[0], dd[1], dd[2], dd[3]);
  po[1] = make_uint4(dd[4], dd[5], dd[6], dd[7]);
  po[2] = make_uint4(dd[8], dd[9], dd[10], dd[11]);
  po[3] = make_uint4(dd[12], dd[13], dd[14], dd[15]);
}

// ---------------- Kernel T: per-row filter threshold (batched LDS staging) ----
__global__ __launch_bounds__(64) void knn_thresh(const uint4* __restrict__ partials,
                                                 unsigned* __restrict__ T0g) {
  __shared__ unsigned sl[64 * 132];      // 33792 B
  int tid = threadIdx.x;
  int row0 = blockIdx.x * 64;
  uint4* sl4 = (uint4*)sl;
  size_t base = (size_t)row0 * 4 + tid;
#define TW(IT, V) { int g2 = ((IT) & 3) * 64 + tid; \
                    sl4[(g2 >> 2) * 33 + ((IT) >> 2) * 4 + (g2 & 3)] = (V); }
#define TB(B) { int IT0 = (B) * 8; \
  uint4 w0 = partials[(size_t)((IT0+0)>>2)*(NROWS*4) + ((IT0+0)&3)*64 + base]; \
  uint4 w1 = partials[(size_t)((IT0+1)>>2)*(NROWS*4) + ((IT0+1)&3)*64 + base]; \
  uint4 w2 = partials[(size_t)((IT0+2)>>2)*(NROWS*4) + ((IT0+2)&3)*64 + base]; \
  uint4 w3 = partials[(size_t)((IT0+3)>>2)*(NROWS*4) + ((IT0+3)&3)*64 + base]; \
  uint4 w4 = partials[(size_t)((IT0+4)>>2)*(NROWS*4) + ((IT0+4)&3)*64 + base]; \
  uint4 w5 = partials[(size_t)((IT0+5)>>2)*(NROWS*4) + ((IT0+5)&3)*64 + base]; \
  uint4 w6 = partials[(size_t)((IT0+6)>>2)*(NROWS*4) + ((IT0+6)&3)*64 + base]; \
  uint4 w7 = partials[(size_t)((IT0+7)>>2)*(NROWS*4) + ((IT0+7)&3)*64 + base]; \
  TW(IT0+0,w0) TW(IT0+1,w1) TW(IT0+2,w2) TW(IT0+3,w3) \
  TW(IT0+4,w4) TW(IT0+5,w5) TW(IT0+6,w6) TW(IT0+7,w7) }
  TB(0) TB(1) TB(2) TB(3)
#undef TB
#undef TW
  __syncthreads();
  unsigned top[16];
#pragma unroll
  for (int s = 0; s < 16; ++s) top[s] = 0xFFFFFFFFu;
  const unsigned* my = sl + tid * 132;
  for (int y = 0; y < 8; ++y) {
#pragma unroll 4
    for (int s = 0; s < 16; ++s) {
      unsigned key = my[y * 16 + s];
      if (key >= top[15]) break;         // chunk list sorted ascending
#pragma unroll
      for (int q2 = 0; q2 < 16; ++q2) {
        unsigned lo = min(key, top[q2]);
        key = max(key, top[q2]);
        top[q2] = lo;
      }
    }
  }
  T0g[row0 + tid] = top[15] & 0xFFFFF000u;
}

// ---------------- Kernel F: full scan + in-register sorted top-16 -------------
// Scan appends to LDS queue (2-op body); epilogue does an unconditional masked
// bubble into a SORTED top-16 (sentinel-padded) — latency hidden by 16 waves/CU.
__global__ __launch_bounds__(256) void knn_filter(const float4* __restrict__ pos4,
                                                  const unsigned* __restrict__ T0g,
                                                  uint4* __restrict__ surv) {
  __shared__ float4 cand[512];
  __shared__ unsigned lq[256 * 28];      // 28 KB
  int t = threadIdx.x;
  int row0 = blockIdx.x * 256;
  int b = row0 >> 12;
  int y = blockIdx.y;
  int j0 = y * 512;
  const float4* pb = pos4 + b * NPTS;
  cand[t] = pb[j0 + t];
  cand[t + 256] = pb[j0 + t + 256];
  __syncthreads();
  int r = row0 + t;
  float4 q = pb[r & (NPTS - 1)];
  unsigned T = T0g[r];
  unsigned cnt = 0;
  unsigned* myq = lq + t * 28;
#pragma unroll 4
  for (int jj = 0; jj < 512; ++jj) {
    float4 c = cand[jj];
    float dx = q.x - c.x, dy = q.y - c.y, dz = q.z - c.z;
    float d = fmaf(dx, dx, fmaf(dy, dy, dz * dz));
    unsigned m = __float_as_uint(d) & 0xFFFFF000u;
    if (m <= T) {
      if (cnt < 28u) myq[cnt] = m | (unsigned)(j0 + jj);
      ++cnt;
    }
  }
  cnt = cnt < 28u ? cnt : 28u;
  // sorted top-16 in registers (all indices literal)
  unsigned t16[16];
#pragma unroll
  for (int s = 0; s < 16; ++s) t16[s] = 0xFFFFFFFFu;
  const uint4* qsrc = (const uint4*)myq;
  uint4 q0 = qsrc[0], q1 = qsrc[1], q2 = qsrc[2], q3 = qsrc[3],
        q4 = qsrc[4], q5 = qsrc[5], q6 = qsrc[6];
#define SIN(K, I) { unsigned key = ((I) < cnt) ? (K) : 0xFFFFFFFFu; bub16u(key, t16); }
  SIN(q0.x,0u) SIN(q0.y,1u) SIN(q0.z,2u) SIN(q0.w,3u)
  SIN(q1.x,4u) SIN(q1.y,5u) SIN(q1.z,6u) SIN(q1.w,7u)
  SIN(q2.x,8u) SIN(q2.y,9u) SIN(q2.z,10u) SIN(q2.w,11u)
  SIN(q3.x,12u) SIN(q3.y,13u) SIN(q3.z,14u) SIN(q3.w,15u)
  SIN(q4.x,16u) SIN(q4.y,17u) SIN(q4.z,18u) SIN(q4.w,19u)
  SIN(q5.x,20u) SIN(q5.y,21u) SIN(q5.z,22u) SIN(q5.w,23u)
  SIN(q6.x,24u) SIN(q6.y,25u) SIN(q6.z,26u) SIN(q6.w,27u)
#undef SIN
  uint4* dst = surv + ((size_t)r * 8 + y) * 4;
  dst[0] = make_uint4(t16[0], t16[1], t16[2], t16[3]);
  dst[1] = make_uint4(t16[4], t16[5], t16[6], t16[7]);
  dst[2] = make_uint4(t16[8], t16[9], t16[10], t16[11]);
  dst[3] = make_uint4(t16[12], t16[13], t16[14], t16[15]);
}

// ---------------- Kernel M: final select (sorted early-break merge) -----------
// Thresh-shaped: 8 sorted 16-lists per row, early-break merge into top-24,
// then r12's exact f64 re-rank + BN stats with per-block partial stores.
__global__ __launch_bounds__(64) void knn_final(const float4* __restrict__ pos4,
                                                const float* __restrict__ invd,
                                                const uint4* __restrict__ surv,
                                                int* __restrict__ nn_idx,
                                                float* __restrict__ dsbuf,
                                                double* __restrict__ stp) {
  __shared__ unsigned sl[64 * 132];      // 33792 B
  int tid = threadIdx.x;
  int row0 = blockIdx.x * 64;
  uint4* sl4 = (uint4*)sl;
  const uint4* sg = surv + (size_t)row0 * 32;   // 32 uint4 per row, contiguous
#define STW(G, V) { int rw = (G) >> 5, of = (G) & 31; sl4[rw * 33 + of] = (V); }
#define LDB(B) { int g0 = (B) * 512 + tid; \
  uint4 v0 = sg[g0], v1 = sg[g0 + 64], v2 = sg[g0 + 128], v3 = sg[g0 + 192], \
        v4 = sg[g0 + 256], v5 = sg[g0 + 320], v6 = sg[g0 + 384], v7 = sg[g0 + 448]; \
  STW(g0, v0) STW(g0 + 64, v1) STW(g0 + 128, v2) STW(g0 + 192, v3) \
  STW(g0 + 256, v4) STW(g0 + 320, v5) STW(g0 + 384, v6) STW(g0 + 448, v7) }
  LDB(0) LDB(1) LDB(2) LDB(3)
#undef LDB
#undef STW
  __syncthreads();

  int r = row0 + tid;
  int b = r >> 12, n = r & (NPTS - 1);

  unsigned top[24];
#pragma unroll
  for (int s = 0; s < 24; ++s) top[s] = 0xFFFFFFFFu;
  const unsigned* my = sl + tid * 132;
  for (int y = 0; y < 8; ++y) {
#pragma unroll 4
    for (int s = 0; s < 16; ++s) {
      unsigned key = my[y * 16 + s];
      if (key >= top[23]) break;         // sorted ascending -> early break
      bub24(key, top);
    }
  }

  // exact f64 re-rank of top-24 survivors — matches numpy-f64
  const float4* pb = pos4 + b * NPTS;
  float4 qp = pb[n];
  double xi = qp.x, yi = qp.y, zi = qp.z;
  double dd[16]; int ii[16];
#pragma unroll
  for (int s = 0; s < 16; ++s) { dd[s] = 1e300; ii[s] = 0; }
#pragma unroll 4
  for (int s = 0; s < 24; ++s) {
    unsigned key = top[s];
    if (key != 0xFFFFFFFFu) {
      int j = (int)(key & 0xFFFu);
      float4 cj = pb[j];
      double dx = xi - (double)cj.x;
      double dy = yi - (double)cj.y;
      double dz = zi - (double)cj.z;
      double dist = dx * dx + dy * dy + dz * dz;
      if (dist < dd[15]) insert16(dist, j, dd, ii);
    }
  }

  const float* ivb = invd + b * NPTS;
  float xv[16];
  float vmax = -1e30f;
#pragma unroll
  for (int s = 0; s < 16; ++s) {
    int j = ii[s];
    nn_idx[(size_t)r * 16 + s] = j;
    float v = ivb[j];
    xv[s] = v;
    vmax = fmaxf(vmax, v);
  }
  double sx = 0, sxx = 0;
  double l1x = 0, l1y = 0, l1z = 0;
  double lxx = 0, lyy = 0, lzz = 0, lxy = 0, lxz = 0, lyz = 0;
#pragma unroll
  for (int s = 0; s < 16; ++s) {
    float x = xv[s] / vmax;
    dsbuf[(size_t)r * 16 + s] = x;
    sx += x; sxx += (double)x * (double)x;
    int j = ii[s];
    float4 cj = pb[j];
    double lx = (double)cj.x - xi;
    double ly = (double)cj.y - yi;
    double lz = (double)cj.z - zi;
    l1x += lx; l1y += ly; l1z += lz;
    lxx += lx * lx; lyy += ly * ly; lzz += lz * lz;
    lxy += lx * ly; lxz += lx * lz; lyz += ly * lz;
  }
  sx  = wave_reduce(sx);  sxx = wave_reduce(sxx);
  l1x = wave_reduce(l1x); l1y = wave_reduce(l1y); l1z = wave_reduce(l1z);
  lxx = wave_reduce(lxx); lyy = wave_reduce(lyy); lzz = wave_reduce(lzz);
  lxy = wave_reduce(lxy); lxz = wave_reduce(lxz); lyz = wave_reduce(lyz);
  if (tid == 0) {
    double* o = stp + (size_t)blockIdx.x * 16;
    o[0] = sx;  o[1] = sxx;
    o[2] = l1x; o[3] = l1y; o[4] = l1z;
    o[5] = lxx; o[6] = lyy; o[7] = lzz;
    o[8] = lxy; o[9] = lxz; o[10] = lyz;
  }
}

// ---------------- Kernel 3: reduce partials + fold BN into affine params ------
__global__ void finalize_params(const double* __restrict__ stp,
                                const float* __restrict__ wn_w,
                                const float* __restrict__ wn_g,
                                const float* __restrict__ wn_be,
                                const float* __restrict__ dn_w1,
                                const float* __restrict__ dn_g1,
                                const float* __restrict__ dn_be1,
                                float* __restrict__ prm) {
  __shared__ double red[11];
  const double M = (double)NROWS * 16.0;  // 262144
  int t = threadIdx.x;
  if (t < 11) {
    double s = 0.0;
#pragma unroll 8
    for (int blk = 0; blk < 256; ++blk) s += stp[(size_t)blk * 16 + t];
    red[t] = s;
  }
  __syncthreads();
  if (t < 32) {
    double m0 = red[2] / M, m1 = red[3] / M, m2 = red[4] / M;
    double cxx = red[5] / M - m0 * m0, cyy = red[6] / M - m1 * m1, czz = red[7] / M - m2 * m2;
    double cxy = red[8] / M - m0 * m1, cxz = red[9] / M - m0 * m2, cyz = red[10] / M - m1 * m2;
    double w0 = wn_w[t * 3], w1 = wn_w[t * 3 + 1], w2 = wn_w[t * 3 + 2];
    double var = w0 * w0 * cxx + w1 * w1 * cyy + w2 * w2 * czz
               + 2.0 * (w0 * w1 * cxy + w0 * w2 * cxz + w1 * w2 * cyz);
    double alpha = (double)wn_g[t] / sqrt(var + 1e-5);
    double a0 = alpha * w0, a1 = alpha * w1, a2 = alpha * w2;
    prm[t * 3] = (float)a0; prm[t * 3 + 1] = (float)a1; prm[t * 3 + 2] = (float)a2;
    prm[96 + t] = (float)((double)wn_be[t] - (a0 * m0 + a1 * m1 + a2 * m2));
  } else if (t < 48) {
    int ch = t - 32;
    double mx = red[0] / M;
    double vx = red[1] / M - mx * mx;
    double w = dn_w1[ch];
    double alpha = (double)dn_g1[ch] * w / sqrt(w * w * vx + 1e-5);
    prm[128 + ch] = (float)alpha;
    prm[144 + ch] = (float)((double)dn_be1[ch] - alpha * mx);
  }
}

// ---------------- Kernel 5: density scale (in-place sigmoid MLP) --------------
__global__ __launch_bounds__(256) void ds_kernel(float* __restrict__ dsbuf,
                                                 const float* __restrict__ prm,
                                                 const float* __restrict__ dn_w2,
                                                 const float* __restrict__ dn_b2) {
  int r = blockIdx.x * 256 + threadIdx.x;
  float A[16], Bp[16], W2[16];
#pragma unroll
  for (int ch = 0; ch < 16; ++ch) {
    A[ch] = prm[128 + ch];
    Bp[ch] = prm[144 + ch];
    W2[ch] = dn_w2[ch];
  }
  float b2 = dn_b2[0];
#pragma unroll
  for (int k = 0; k < 16; ++k) {
    float x = dsbuf[(size_t)r * 16 + k];
    float s = b2;
#pragma unroll
    for (int ch = 0; ch < 16; ++ch) s = fmaf(W2[ch], fmaxf(fmaf(A[ch], x, Bp[ch]), 0.f), s);
    dsbuf[(size_t)r * 16 + k] = 1.f / (1.f + expf(-s));
  }
}

// ---------------- Kernel T: transpose inputs (B,C,N) f32 -> (B,N,C) bf16 ------
__global__ __launch_bounds__(256) void transpose_in(const float* __restrict__ in,
                                                    ushort* __restrict__ inT) {
  __shared__ float tile[64][68];
  int t = threadIdx.x;
  int b = blockIdx.x >> 6;
  int n0 = (blockIdx.x & 63) << 6;
  {
    int c = t >> 2, q = t & 3;
    const float* src = in + ((size_t)(b * 64 + c)) * NPTS + n0 + q * 16;
    float4 v0 = ((const float4*)src)[0];
    float4 v1 = ((const float4*)src)[1];
    float4 v2 = ((const float4*)src)[2];
    float4 v3 = ((const float4*)src)[3];
    *(float4*)&tile[c][q * 16 + 0] = v0;
    *(float4*)&tile[c][q * 16 + 4] = v1;
    *(float4*)&tile[c][q * 16 + 8] = v2;
    *(float4*)&tile[c][q * 16 + 12] = v3;
  }
  __syncthreads();
  {
    int nl = t >> 2, cq = t & 3;
    unsigned pk[8];
#pragma unroll
    for (int i = 0; i < 8; ++i) {
      float lo = tile[cq * 16 + 2 * i][nl];
      float hi = tile[cq * 16 + 2 * i + 1][nl];
      pk[i] = pk2(lo, hi);
    }
    uint4* dst = (uint4*)(inT + ((size_t)(b * NPTS + n0 + nl)) * 64 + cq * 16);
    dst[0] = make_uint4(pk[0], pk[1], pk[2], pk[3]);
    dst[1] = make_uint4(pk[4], pk[5], pk[6], pk[7]);
  }
}

// ---------------- Kernel L: pack lin_w into B-fragment order (bf16) -----------
__global__ __launch_bounds__(256) void prep_LTf(const float* __restrict__ lin_w,
                                                ushort* __restrict__ LTf) {
  int g = blockIdx.x * 256 + threadIdx.x;   // 16384
  int l = g & 63, ot = (g >> 6) & 3, s = g >> 8;
  int o = ot * 16 + (l & 15);
  const float* src = lin_w + (size_t)o * 2048 + s * 32 + (l >> 4) * 8;
  float4 u0 = ((const float4*)src)[0];
  float4 u1 = ((const float4*)src)[1];
  ((uint4*)LTf)[g] = make_uint4(pk2(u0.x, u0.y), pk2(u0.z, u0.w),
                                pk2(u1.x, u1.y), pk2(u1.z, u1.w));
}

// ------- Fused kernel: gather + WeightNet + per-point matmul + MFMA GEMM ------
#define XSTR 2320   // bytes per point: 16 k-rows * 144B (128 data + 16 pad)
#define WSTR 524    // f32 per point: 16 k * 32 w + 12 pad

#define FMA_ROW(c) \
  a##c##_0 += W0 * (f32x4)x##c; a##c##_1 += W1 * (f32x4)x##c; \
  a##c##_2 += W2 * (f32x4)x##c; a##c##_3 += W3 * (f32x4)x##c; \
  a##c##_4 += W4 * (f32x4)x##c; a##c##_5 += W5 * (f32x4)x##c; \
  a##c##_6 += W6 * (f32x4)x##c; a##c##_7 += W7 * (f32x4)x##c;

#define WRITE_C(ci, csval) \
  { size_t base = ((size_t)(csval)) * 64 + pl; \
    aq[base +  0] = make_uint4(pk2(a##ci##_0.x, a##ci##_0.y), pk2(a##ci##_0.z, a##ci##_0.w), \
                               pk2(a##ci##_1.x, a##ci##_1.y), pk2(a##ci##_1.z, a##ci##_1.w)); \
    aq[base + 16] = make_uint4(pk2(a##ci##_2.x, a##ci##_2.y), pk2(a##ci##_2.z, a##ci##_2.w), \
                               pk2(a##ci##_3.x, a##ci##_3.y), pk2(a##ci##_3.z, a##ci##_3.w)); \
    aq[base + 32] = make_uint4(pk2(a##ci##_4.x, a##ci##_4.y), pk2(a##ci##_4.z, a##ci##_4.w), \
                               pk2(a##ci##_5.x, a##ci##_5.y), pk2(a##ci##_5.z, a##ci##_5.w)); \
    aq[base + 48] = make_uint4(pk2(a##ci##_6.x, a##ci##_6.y), pk2(a##ci##_6.z, a##ci##_6.w), \
                               pk2(a##ci##_7.x, a##ci##_7.y), pk2(a##ci##_7.z, a##ci##_7.w)); }

__global__ __launch_bounds__(256, 2) void fused(const ushort* __restrict__ inT,
                                                const float4* __restrict__ pos4,
                                                const int* __restrict__ nn_idx,
                                                const float* __restrict__ dsbuf,
                                                const float* __restrict__ prm_g,
                                                const ushort* __restrict__ LTf,
                                                const float* __restrict__ lin_b,
                                                float* __restrict__ out) {
  __shared__ __align__(16) char smem[16 * XSTR + 16 * WSTR * 4];  // 70656 B
  __shared__ float prms[128];
  char* xraw = smem;
  float* wlds = (float*)(smem + 16 * XSTR);
  int t = threadIdx.x;
  int blk = blockIdx.x;          // 1024 tiles of 16 points
  int b = blk >> 8;
  int n0 = (blk & 255) << 4;
  if (t < 128) prms[t] = prm_g[t];
  __syncthreads();
  // ---- phase 1: stage. thread (k = t>>4, p = t&15) ----
  {
    int k = t >> 4, p = t & 15;
    int r = blk * 16 + p;
    int n = n0 + p;
    int j = nn_idx[(size_t)r * 16 + k];
    float4 pj = pos4[b * NPTS + j];
    float4 pn = pos4[b * NPTS + n];
    float lx = pj.x - pn.x, ly = pj.y - pn.y, lz = pj.z - pn.z;
    float ds = dsbuf[(size_t)r * 16 + k];
    const uint4* srcx = (const uint4*)(inT + ((size_t)(b * NPTS + j)) * 64);
    uint4* dstx = (uint4*)(xraw + p * XSTR + k * 144);
#pragma unroll
    for (int i = 0; i < 8; ++i) dstx[i] = srcx[i];
    float* wr = wlds + p * WSTR + k * 32;
#pragma unroll
    for (int w = 0; w < 32; ++w) {
      float v = fmaf(prms[w * 3], lx,
                fmaf(prms[w * 3 + 1], ly,
                fmaf(prms[w * 3 + 2], lz, prms[96 + w])));
      wr[w] = fmaxf(v, 0.f) * ds;
    }
  }
  __syncthreads();
  // ---- phase 2: feat in NAMED registers. thread (pl = t&15, cl = t>>4) ----
  int pl = t & 15, cl = t >> 4;
  f32x4 a0_0=(f32x4)0.f, a0_1=(f32x4)0.f, a0_2=(f32x4)0.f, a0_3=(f32x4)0.f,
        a0_4=(f32x4)0.f, a0_5=(f32x4)0.f, a0_6=(f32x4)0.f, a0_7=(f32x4)0.f;
  f32x4 a1_0=(f32x4)0.f, a1_1=(f32x4)0.f, a1_2=(f32x4)0.f, a1_3=(f32x4)0.f,
        a1_4=(f32x4)0.f, a1_5=(f32x4)0.f, a1_6=(f32x4)0.f, a1_7=(f32x4)0.f;
  f32x4 a2_0=(f32x4)0.f, a2_1=(f32x4)0.f, a2_2=(f32x4)0.f, a2_3=(f32x4)0.f,
        a2_4=(f32x4)0.f, a2_5=(f32x4)0.f, a2_6=(f32x4)0.f, a2_7=(f32x4)0.f;
  f32x4 a3_0=(f32x4)0.f, a3_1=(f32x4)0.f, a3_2=(f32x4)0.f, a3_3=(f32x4)0.f,
        a3_4=(f32x4)0.f, a3_5=(f32x4)0.f, a3_6=(f32x4)0.f, a3_7=(f32x4)0.f;
  {
    const char* xrow = xraw + pl * XSTR;
    const float* wp = wlds + pl * WSTR;
#pragma unroll 4
    for (int kk = 0; kk < 16; ++kk) {
      unsigned xa = *(const unsigned*)(xrow + kk * 144 + cl * 4);        // ch 2cl,2cl+1
      unsigned xb = *(const unsigned*)(xrow + kk * 144 + 64 + cl * 4);   // ch 32+2cl,33+2cl
      float x0 = __uint_as_float(xa << 16);
      float x1 = __uint_as_float(xa & 0xFFFF0000u);
      float x2 = __uint_as_float(xb << 16);
      float x3 = __uint_as_float(xb & 0xFFFF0000u);
      const f32x4* wk = (const f32x4*)(wp + kk * 32);
      f32x4 W0 = wk[0], W1 = wk[1], W2 = wk[2], W3 = wk[3];
      f32x4 W4 = wk[4], W5 = wk[5], W6 = wk[6], W7 = wk[7];
      FMA_ROW(0)
      FMA_ROW(1)
      FMA_ROW(2)
      FMA_ROW(3)
    }
  }
  __syncthreads();   // everyone done reading xraw/wlds
  // ---- phase 3: write A-frags (bf16) over the staging LDS (64 KB) ----
  uint4* aq = (uint4*)smem;
  WRITE_C(0, 2 * cl)
  WRITE_C(1, 2 * cl + 1)
  WRITE_C(2, 32 + 2 * cl)
  WRITE_C(3, 33 + 2 * cl)
  __syncthreads();
  // ---- phase 4: MFMA GEMM. wave wv owns output tile ot=wv, full K ----
  {
    int wv = t >> 6, l = t & 63;
    const uint4* Lq = (const uint4*)LTf;
    f32x4 cacc = (f32x4)0.f;
#pragma unroll 4
    for (int s = 0; s < 64; ++s) {
      uint4 ua = aq[s * 64 + l];
      uint4 ub = Lq[(s * 4 + wv) * 64 + l];
      bf16x8 A = *reinterpret_cast<bf16x8*>(&ua);
      bf16x8 B = *reinterpret_cast<bf16x8*>(&ub);
      cacc = __builtin_amdgcn_mfma_f32_16x16x32_bf16(A, B, cacc, 0, 0, 0);
    }
    int o = wv * 16 + (l & 15);
    float bias = lin_b[o];
    cacc.x += bias; cacc.y += bias; cacc.z += bias; cacc.w += bias;
    *(f32x4*)(out + ((size_t)(b * 64 + o)) * NPTS + n0 + (l >> 4) * 4) = cacc;
  }
}

// ------------------------------- launch ---------------------------------------
extern "C" void kernel_launch(void* const* d_in, const int* in_sizes, int n_in,
                              void* d_out, int out_size, void* d_ws, size_t ws_size,
                              hipStream_t stream) {
  (void)in_sizes; (void)n_in; (void)out_size; (void)ws_size;
  const float* inputs = (const float*)d_in[0];
  const float* pos    = (const float*)d_in[1];
  const float* invd   = (const float*)d_in[2];
  const float* wn_w   = (const float*)d_in[3];
  const float* wn_g   = (const float*)d_in[5];
  const float* wn_be  = (const float*)d_in[6];
  const float* dn_w1  = (const float*)d_in[7];
  const float* dn_g1  = (const float*)d_in[9];
  const float* dn_be1 = (const float*)d_in[10];
  const float* dn_w2  = (const float*)d_in[11];
  const float* dn_b2  = (const float*)d_in[12];
  const float* lin_w  = (const float*)d_in[13];
  const float* lin_b  = (const float*)d_in[14];
  float* outp = (float*)d_out;

  char* ws = (char*)d_ws;
  double*   stp      = (double*)(ws + 294912);                // 32 KB  (256 x 16 dbl)
  float*    prm      = (float*)(ws + 1024);                   // 640 B
  float4*   pos4     = (float4*)(ws + 4096);                  // 256 KB
  int*      nnidx    = (int*)(ws + (size_t)(1u << 19));       // 1 MB   [0.5, 1.5)
  float*    dsbuf    = (float*)(ws + (size_t)(3u << 19));     // 1 MB   [1.5, 2.5)
  ushort*   inT      = (ushort*)(ws + (size_t)(5u << 19));    // 2 MB   [2.5, 4.5)
  ushort*   LTf      = (ushort*)(ws + (size_t)(9u << 19));    // 256 KB [4.5, 4.75)
  unsigned* T0g      = (unsigned*)(ws + (size_t)(19u << 18)); // 64 KB  [4.75, ...)
  uint4*    partials = (uint4*)(ws + (size_t)(11u << 19));    // 8 MB   [5.5, 13.5)
  uint4*    surv     = (uint4*)(ws + (size_t)(27u << 19));    // 8 MB   [13.5, 21.5)

  pack_pos4<<<64, 256, 0, stream>>>(pos, pos4);
  transpose_in<<<256, 256, 0, stream>>>(inputs, inT);
  prep_LTf<<<64, 256, 0, stream>>>(lin_w, LTf);
  knn_sub<<<dim3(64, 8), 256, 0, stream>>>(pos4, partials);
  knn_thresh<<<256, 64, 0, stream>>>(partials, T0g);
  knn_filter<<<dim3(64, 8), 256, 0, stream>>>(pos4, T0g, surv);
  knn_final<<<256, 64, 0, stream>>>(pos4, invd, surv, nnidx, dsbuf, stp);
  finalize_params<<<1, 64, 0, stream>>>(stp, wn_w, wn_g, wn_be, dn_w1, dn_g1, dn_be1, prm);
  ds_kernel<<<64, 256, 0, stream>>>(dsbuf, prm, dn_w2, dn_b2);
  fused<<<1024, 256, 0, stream>>>(inT, pos4, nnidx, dsbuf, prm, LTf, lin_b, outp);
}

// Round 16
// 167.313 us; speedup vs baseline: 1.2716x; 1.0607x over previous
//
#include <hip/hip_runtime.h>
#include <math.h>

// Problem constants
#define NB 4
#define NC 64
#define NPTS 4096
#define NROWS (NB*NPTS)      // 16384

typedef __attribute__((ext_vector_type(4))) float f32x4;
typedef __bf16 bf16x8 __attribute__((ext_vector_type(8)));

__device__ __forceinline__ ushort f2bf(float f) {
  unsigned u = __float_as_uint(f);
  u = (u + 0x7FFFu + ((u >> 16) & 1u)) >> 16;   // RNE
  return (ushort)u;
}
__device__ __forceinline__ unsigned pk2(float lo, float hi) {
  return (unsigned)f2bf(lo) | ((unsigned)f2bf(hi) << 16);
}

// ---------------- top-16 insertion (sorted ascending, dd[15]=max) -------------
__device__ __forceinline__ void insert16(double dist, int j, double (&dd)[16], int (&ii)[16]) {
  double cd = dist; int ci = j;
#pragma unroll
  for (int s = 0; s < 16; ++s) {
    double od = dd[s]; int oi = ii[s];
    bool c = cd < od;
    dd[s] = c ? cd : od;
    ii[s] = c ? ci : oi;
    cd = c ? od : cd;
    ci = c ? oi : ci;
  }
}

__device__ __forceinline__ void bub24(unsigned key, unsigned (&top)[24]) {
#pragma unroll
  for (int q2 = 0; q2 < 24; ++q2) {
    unsigned lo = min(key, top[q2]);
    key = max(key, top[q2]);
    top[q2] = lo;
  }
}

__device__ __forceinline__ void bub16u(unsigned key, unsigned (&t)[16]) {
#pragma unroll
  for (int q2 = 0; q2 < 16; ++q2) {
    unsigned lo = min(key, t[q2]);
    key = max(key, t[q2]);
    t[q2] = lo;
  }
}

__device__ __forceinline__ double wave_reduce(double v) {
#pragma unroll
  for (int off = 32; off; off >>= 1) v += __shfl_down(v, off, 64);
  return v;
}

// ---------------- Kernel 0: pack positions as float4 --------------------------
__global__ __launch_bounds__(256) void pack_pos4(const float* __restrict__ pos,
                                                 float4* __restrict__ pos4) {
  int g = blockIdx.x * 256 + threadIdx.x;   // 4*4096 total
  int b = g >> 12, n = g & (NPTS - 1);
  const float* pb = pos + b * 3 * NPTS;
  pos4[g] = make_float4(pb[n], pb[NPTS + n], pb[2 * NPTS + n], 0.f);
}

// ---------------- Kernel S: subset partial KNN --------------------------------
// Subset = first 256 of each 1024-quarter (1024 candidates/row), 8 chunks of 128.
__global__ __launch_bounds__(256) void knn_sub(const float4* __restrict__ pos4,
                                               uint4* __restrict__ partials) {
  __shared__ float4 cand[128];
  int t = threadIdx.x;
  int row0 = blockIdx.x * 256;
  int b = row0 >> 12;
  int y = blockIdx.y;
  int j0 = (y >> 1) * 1024 + (y & 1) * 128;
  const float4* pb = pos4 + b * NPTS;
  if (t < 128) cand[t] = pb[j0 + t];
  __syncthreads();
  float4 q = pb[(row0 + t) & (NPTS - 1)];
  unsigned dd[16];
#pragma unroll
  for (int s = 0; s < 16; ++s) dd[s] = 0xFFFFFFFFu;
#pragma unroll 4
  for (int jj = 0; jj < 128; ++jj) {
    float4 c = cand[jj];
    float dx = q.x - c.x, dy = q.y - c.y, dz = q.z - c.z;
    float d = fmaf(dx, dx, fmaf(dy, dy, dz * dz));
    unsigned key = (__float_as_uint(d) & 0xFFFFF000u) | (unsigned)(j0 + jj);
#pragma unroll
    for (int s = 0; s < 16; ++s) {
      unsigned lo = min(key, dd[s]);
      key = max(key, dd[s]);
      dd[s] = lo;
    }
  }
  uint4* po = partials + ((size_t)y * NROWS + row0 + t) * 4;
  po[0] = make_uint4(dd[0], dd[1], dd[2], dd[3]);
  po[1] = make_uint4(dd[4], dd[5], dd[6], dd[7]);
  po[2] = make_uint4(dd[8], dd[9], dd[10], dd[11]);
  po[3] = make_uint4(dd[12], dd[13], dd[14], dd[15]);
}

// ---------------- Kernel T: per-row filter threshold (batched LDS staging) ----
__global__ __launch_bounds__(64) void knn_thresh(const uint4* __restrict__ partials,
                                                 unsigned* __restrict__ T0g) {
  __shared__ unsigned sl[64 * 132];      // 33792 B
  int tid = threadIdx.x;
  int row0 = blockIdx.x * 64;
  uint4* sl4 = (uint4*)sl;
  size_t base = (size_t)row0 * 4 + tid;
#define TW(IT, V) { int g2 = ((IT) & 3) * 64 + tid; \
                    sl4[(g2 >> 2) * 33 + ((IT) >> 2) * 4 + (g2 & 3)] = (V); }
#define TB(B) { int IT0 = (B) * 8; \
  uint4 w0 = partials[(size_t)((IT0+0)>>2)*(NROWS*4) + ((IT0+0)&3)*64 + base]; \
  uint4 w1 = partials[(size_t)((IT0+1)>>2)*(NROWS*4) + ((IT0+1)&3)*64 + base]; \
  uint4 w2 = partials[(size_t)((IT0+2)>>2)*(NROWS*4) + ((IT0+2)&3)*64 + base]; \
  uint4 w3 = partials[(size_t)((IT0+3)>>2)*(NROWS*4) + ((IT0+3)&3)*64 + base]; \
  uint4 w4 = partials[(size_t)((IT0+4)>>2)*(NROWS*4) + ((IT0+4)&3)*64 + base]; \
  uint4 w5 = partials[(size_t)((IT0+5)>>2)*(NROWS*4) + ((IT0+5)&3)*64 + base]; \
  uint4 w6 = partials[(size_t)((IT0+6)>>2)*(NROWS*4) + ((IT0+6)&3)*64 + base]; \
  uint4 w7 = partials[(size_t)((IT0+7)>>2)*(NROWS*4) + ((IT0+7)&3)*64 + base]; \
  TW(IT0+0,w0) TW(IT0+1,w1) TW(IT0+2,w2) TW(IT0+3,w3) \
  TW(IT0+4,w4) TW(IT0+5,w5) TW(IT0+6,w6) TW(IT0+7,w7) }
  TB(0) TB(1) TB(2) TB(3)
#undef TB
#undef TW
  __syncthreads();
  unsigned top[16];
#pragma unroll
  for (int s = 0; s < 16; ++s) top[s] = 0xFFFFFFFFu;
  const unsigned* my = sl + tid * 132;
  for (int y = 0; y < 8; ++y) {
#pragma unroll 4
    for (int s = 0; s < 16; ++s) {
      unsigned key = my[y * 16 + s];
      if (key >= top[15]) break;         // chunk list sorted ascending
#pragma unroll
      for (int q2 = 0; q2 < 16; ++q2) {
        unsigned lo = min(key, top[q2]);
        key = max(key, top[q2]);
        top[q2] = lo;
      }
    }
  }
  T0g[row0 + tid] = top[15] & 0xFFFFF000u;
}

// ---------------- Kernel F: scan 256-cand chunk + sorted top-16 ---------------
// 16 chunks/row (grid 64x16 = 1024 blocks = 4/CU -> 16 waves/CU). Scan appends
// to LDS queue (2-op body); epilogue bubbles into sorted sentinel-padded top-16.
__global__ __launch_bounds__(256) void knn_filter(const float4* __restrict__ pos4,
                                                  const unsigned* __restrict__ T0g,
                                                  uint4* __restrict__ surv) {
  __shared__ float4 cand[256];           // 4 KB
  __shared__ unsigned lq[256 * 28];      // 28 KB
  int t = threadIdx.x;
  int row0 = blockIdx.x * 256;
  int b = row0 >> 12;
  int y = blockIdx.y;
  int j0 = y * 256;
  const float4* pb = pos4 + b * NPTS;
  cand[t] = pb[j0 + t];
  __syncthreads();
  int r = row0 + t;
  float4 q = pb[r & (NPTS - 1)];
  unsigned T = T0g[r];
  unsigned cnt = 0;
  unsigned* myq = lq + t * 28;
#pragma unroll 4
  for (int jj = 0; jj < 256; ++jj) {
    float4 c = cand[jj];
    float dx = q.x - c.x, dy = q.y - c.y, dz = q.z - c.z;
    float d = fmaf(dx, dx, fmaf(dy, dy, dz * dz));
    unsigned m = __float_as_uint(d) & 0xFFFFF000u;
    if (m <= T) {
      if (cnt < 28u) myq[cnt] = m | (unsigned)(j0 + jj);
      ++cnt;
    }
  }
  cnt = cnt < 28u ? cnt : 28u;
  unsigned t16[16];
#pragma unroll
  for (int s = 0; s < 16; ++s) t16[s] = 0xFFFFFFFFu;
  const uint4* qsrc = (const uint4*)myq;
  uint4 q0 = qsrc[0], q1 = qsrc[1], q2 = qsrc[2], q3 = qsrc[3],
        q4 = qsrc[4], q5 = qsrc[5], q6 = qsrc[6];
#define SIN(K, I) { unsigned key = ((I) < cnt) ? (K) : 0xFFFFFFFFu; bub16u(key, t16); }
  SIN(q0.x,0u) SIN(q0.y,1u) SIN(q0.z,2u) SIN(q0.w,3u)
  SIN(q1.x,4u) SIN(q1.y,5u) SIN(q1.z,6u) SIN(q1.w,7u)
  SIN(q2.x,8u) SIN(q2.y,9u) SIN(q2.z,10u) SIN(q2.w,11u)
  SIN(q3.x,12u) SIN(q3.y,13u) SIN(q3.z,14u) SIN(q3.w,15u)
  SIN(q4.x,16u) SIN(q4.y,17u) SIN(q4.z,18u) SIN(q4.w,19u)
  SIN(q5.x,20u) SIN(q5.y,21u) SIN(q5.z,22u) SIN(q5.w,23u)
  SIN(q6.x,24u) SIN(q6.y,25u) SIN(q6.z,26u) SIN(q6.w,27u)
#undef SIN
  uint4* dst = surv + ((size_t)r * 16 + y) * 4;
  dst[0] = make_uint4(t16[0], t16[1], t16[2], t16[3]);
  dst[1] = make_uint4(t16[4], t16[5], t16[6], t16[7]);
  dst[2] = make_uint4(t16[8], t16[9], t16[10], t16[11]);
  dst[3] = make_uint4(t16[12], t16[13], t16[14], t16[15]);
}

// ---------------- Kernel M: final select (16 sorted lists, early-break) -------
__global__ __launch_bounds__(64) void knn_final(const float4* __restrict__ pos4,
                                                const float* __restrict__ invd,
                                                const uint4* __restrict__ surv,
                                                int* __restrict__ nn_idx,
                                                float* __restrict__ dsbuf,
                                                double* __restrict__ stp) {
  __shared__ unsigned sl[64 * 264];      // 67584 B
  int tid = threadIdx.x;
  int row0 = blockIdx.x * 64;
  uint4* sl4 = (uint4*)sl;
  const uint4* sg = surv + (size_t)row0 * 64;   // 64 uint4 per row, contiguous
#define STW(G, V) { int rw = (G) >> 6, of = (G) & 63; sl4[rw * 66 + of] = (V); }
#define LDB(B) { int g0 = (B) * 512 + tid; \
  uint4 v0 = sg[g0], v1 = sg[g0 + 64], v2 = sg[g0 + 128], v3 = sg[g0 + 192], \
        v4 = sg[g0 + 256], v5 = sg[g0 + 320], v6 = sg[g0 + 384], v7 = sg[g0 + 448]; \
  STW(g0, v0) STW(g0 + 64, v1) STW(g0 + 128, v2) STW(g0 + 192, v3) \
  STW(g0 + 256, v4) STW(g0 + 320, v5) STW(g0 + 384, v6) STW(g0 + 448, v7) }
  LDB(0) LDB(1) LDB(2) LDB(3) LDB(4) LDB(5) LDB(6) LDB(7)
#undef LDB
#undef STW
  __syncthreads();

  int r = row0 + tid;
  int b = r >> 12, n = r & (NPTS - 1);

  unsigned top[24];
#pragma unroll
  for (int s = 0; s < 24; ++s) top[s] = 0xFFFFFFFFu;
  const unsigned* my = sl + tid * 264;
  for (int y = 0; y < 16; ++y) {
#pragma unroll 4
    for (int s = 0; s < 16; ++s) {
      unsigned key = my[y * 16 + s];
      if (key >= top[23]) break;         // sorted ascending -> early break
      bub24(key, top);
    }
  }

  // exact f64 re-rank of top-24 survivors — matches numpy-f64
  const float4* pb = pos4 + b * NPTS;
  float4 qp = pb[n];
  double xi = qp.x, yi = qp.y, zi = qp.z;
  double dd[16]; int ii[16];
#pragma unroll
  for (int s = 0; s < 16; ++s) { dd[s] = 1e300; ii[s] = 0; }
#pragma unroll 4
  for (int s = 0; s < 24; ++s) {
    unsigned key = top[s];
    if (key != 0xFFFFFFFFu) {
      int j = (int)(key & 0xFFFu);
      float4 cj = pb[j];
      double dx = xi - (double)cj.x;
      double dy = yi - (double)cj.y;
      double dz = zi - (double)cj.z;
      double dist = dx * dx + dy * dy + dz * dz;
      if (dist < dd[15]) insert16(dist, j, dd, ii);
    }
  }

  const float* ivb = invd + b * NPTS;
  float xv[16];
  float vmax = -1e30f;
#pragma unroll
  for (int s = 0; s < 16; ++s) {
    int j = ii[s];
    nn_idx[(size_t)r * 16 + s] = j;
    float v = ivb[j];
    xv[s] = v;
    vmax = fmaxf(vmax, v);
  }
  double sx = 0, sxx = 0;
  double l1x = 0, l1y = 0, l1z = 0;
  double lxx = 0, lyy = 0, lzz = 0, lxy = 0, lxz = 0, lyz = 0;
#pragma unroll
  for (int s = 0; s < 16; ++s) {
    float x = xv[s] / vmax;
    dsbuf[(size_t)r * 16 + s] = x;
    sx += x; sxx += (double)x * (double)x;
    int j = ii[s];
    float4 cj = pb[j];
    double lx = (double)cj.x - xi;
    double ly = (double)cj.y - yi;
    double lz = (double)cj.z - zi;
    l1x += lx; l1y += ly; l1z += lz;
    lxx += lx * lx; lyy += ly * ly; lzz += lz * lz;
    lxy += lx * ly; lxz += lx * lz; lyz += ly * lz;
  }
  sx  = wave_reduce(sx);  sxx = wave_reduce(sxx);
  l1x = wave_reduce(l1x); l1y = wave_reduce(l1y); l1z = wave_reduce(l1z);
  lxx = wave_reduce(lxx); lyy = wave_reduce(lyy); lzz = wave_reduce(lzz);
  lxy = wave_reduce(lxy); lxz = wave_reduce(lxz); lyz = wave_reduce(lyz);
  if (tid == 0) {
    double* o = stp + (size_t)blockIdx.x * 16;
    o[0] = sx;  o[1] = sxx;
    o[2] = l1x; o[3] = l1y; o[4] = l1z;
    o[5] = lxx; o[6] = lyy; o[7] = lzz;
    o[8] = lxy; o[9] = lxz; o[10] = lyz;
  }
}

// ---------------- Kernel 3: reduce partials + fold BN into affine params ------
__global__ void finalize_params(const double* __restrict__ stp,
                                const float* __restrict__ wn_w,
                                const float* __restrict__ wn_g,
                                const float* __restrict__ wn_be,
                                const float* __restrict__ dn_w1,
                                const float* __restrict__ dn_g1,
                                const float* __restrict__ dn_be1,
                                float* __restrict__ prm) {
  __shared__ double red[11];
  const double M = (double)NROWS * 16.0;  // 262144
  int t = threadIdx.x;
  if (t < 11) {
    double s = 0.0;
#pragma unroll 8
    for (int blk = 0; blk < 256; ++blk) s += stp[(size_t)blk * 16 + t];
    red[t] = s;
  }
  __syncthreads();
  if (t < 32) {
    double m0 = red[2] / M, m1 = red[3] / M, m2 = red[4] / M;
    double cxx = red[5] / M - m0 * m0, cyy = red[6] / M - m1 * m1, czz = red[7] / M - m2 * m2;
    double cxy = red[8] / M - m0 * m1, cxz = red[9] / M - m0 * m2, cyz = red[10] / M - m1 * m2;
    double w0 = wn_w[t * 3], w1 = wn_w[t * 3 + 1], w2 = wn_w[t * 3 + 2];
    double var = w0 * w0 * cxx + w1 * w1 * cyy + w2 * w2 * czz
               + 2.0 * (w0 * w1 * cxy + w0 * w2 * cxz + w1 * w2 * cyz);
    double alpha = (double)wn_g[t] / sqrt(var + 1e-5);
    double a0 = alpha * w0, a1 = alpha * w1, a2 = alpha * w2;
    prm[t * 3] = (float)a0; prm[t * 3 + 1] = (float)a1; prm[t * 3 + 2] = (float)a2;
    prm[96 + t] = (float)((double)wn_be[t] - (a0 * m0 + a1 * m1 + a2 * m2));
  } else if (t < 48) {
    int ch = t - 32;
    double mx = red[0] / M;
    double vx = red[1] / M - mx * mx;
    double w = dn_w1[ch];
    double alpha = (double)dn_g1[ch] * w / sqrt(w * w * vx + 1e-5);
    prm[128 + ch] = (float)alpha;
    prm[144 + ch] = (float)((double)dn_be1[ch] - alpha * mx);
  }
}

// ---------------- Kernel 5: density scale (in-place sigmoid MLP) --------------
__global__ __launch_bounds__(256) void ds_kernel(float* __restrict__ dsbuf,
                                                 const float* __restrict__ prm,
                                                 const float* __restrict__ dn_w2,
                                                 const float* __restrict__ dn_b2) {
  int r = blockIdx.x * 256 + threadIdx.x;
  float A[16], Bp[16], W2[16];
#pragma unroll
  for (int ch = 0; ch < 16; ++ch) {
    A[ch] = prm[128 + ch];
    Bp[ch] = prm[144 + ch];
    W2[ch] = dn_w2[ch];
  }
  float b2 = dn_b2[0];
#pragma unroll
  for (int k = 0; k < 16; ++k) {
    float x = dsbuf[(size_t)r * 16 + k];
    float s = b2;
#pragma unroll
    for (int ch = 0; ch < 16; ++ch) s = fmaf(W2[ch], fmaxf(fmaf(A[ch], x, Bp[ch]), 0.f), s);
    dsbuf[(size_t)r * 16 + k] = 1.f / (1.f + expf(-s));
  }
}

// ---------------- Kernel T: transpose inputs (B,C,N) f32 -> (B,N,C) bf16 ------
__global__ __launch_bounds__(256) void transpose_in(const float* __restrict__ in,
                                                    ushort* __restrict__ inT) {
  __shared__ float tile[64][68];
  int t = threadIdx.x;
  int b = blockIdx.x >> 6;
  int n0 = (blockIdx.x & 63) << 6;
  {
    int c = t >> 2, q = t & 3;
    const float* src = in + ((size_t)(b * 64 + c)) * NPTS + n0 + q * 16;
    float4 v0 = ((const float4*)src)[0];
    float4 v1 = ((const float4*)src)[1];
    float4 v2 = ((const float4*)src)[2];
    float4 v3 = ((const float4*)src)[3];
    *(float4*)&tile[c][q * 16 + 0] = v0;
    *(float4*)&tile[c][q * 16 + 4] = v1;
    *(float4*)&tile[c][q * 16 + 8] = v2;
    *(float4*)&tile[c][q * 16 + 12] = v3;
  }
  __syncthreads();
  {
    int nl = t >> 2, cq = t & 3;
    unsigned pk[8];
#pragma unroll
    for (int i = 0; i < 8; ++i) {
      float lo = tile[cq * 16 + 2 * i][nl];
      float hi = tile[cq * 16 + 2 * i + 1][nl];
      pk[i] = pk2(lo, hi);
    }
    uint4* dst = (uint4*)(inT + ((size_t)(b * NPTS + n0 + nl)) * 64 + cq * 16);
    dst[0] = make_uint4(pk[0], pk[1], pk[2], pk[3]);
    dst[1] = make_uint4(pk[4], pk[5], pk[6], pk[7]);
  }
}

// ---------------- Kernel L: pack lin_w into B-fragment order (bf16) -----------
__global__ __launch_bounds__(256) void prep_LTf(const float* __restrict__ lin_w,
                                                ushort* __restrict__ LTf) {
  int g = blockIdx.x * 256 + threadIdx.x;   // 16384
  int l = g & 63, ot = (g >> 6) & 3, s = g >> 8;
  int o = ot * 16 + (l & 15);
  const float* src = lin_w + (size_t)o * 2048 + s * 32 + (l >> 4) * 8;
  float4 u0 = ((const float4*)src)[0];
  float4 u1 = ((const float4*)src)[1];
  ((uint4*)LTf)[g] = make_uint4(pk2(u0.x, u0.y), pk2(u0.z, u0.w),
                                pk2(u1.x, u1.y), pk2(u1.z, u1.w));
}

// ------- Fused kernel: gather + WeightNet + per-point matmul + MFMA GEMM ------
#define XSTR 2320   // bytes per point: 16 k-rows * 144B (128 data + 16 pad)
#define WSTR 524    // f32 per point: 16 k * 32 w + 12 pad

#define FMA_ROW(c) \
  a##c##_0 += W0 * (f32x4)x##c; a##c##_1 += W1 * (f32x4)x##c; \
  a##c##_2 += W2 * (f32x4)x##c; a##c##_3 += W3 * (f32x4)x##c; \
  a##c##_4 += W4 * (f32x4)x##c; a##c##_5 += W5 * (f32x4)x##c; \
  a##c##_6 += W6 * (f32x4)x##c; a##c##_7 += W7 * (f32x4)x##c;

#define WRITE_C(ci, csval) \
  { size_t base = ((size_t)(csval)) * 64 + pl; \
    aq[base +  0] = make_uint4(pk2(a##ci##_0.x, a##ci##_0.y), pk2(a##ci##_0.z, a##ci##_0.w), \
                               pk2(a##ci##_1.x, a##ci##_1.y), pk2(a##ci##_1.z, a##ci##_1.w)); \
    aq[base + 16] = make_uint4(pk2(a##ci##_2.x, a##ci##_2.y), pk2(a##ci##_2.z, a##ci##_2.w), \
                               pk2(a##ci##_3.x, a##ci##_3.y), pk2(a##ci##_3.z, a##ci##_3.w)); \
    aq[base + 32] = make_uint4(pk2(a##ci##_4.x, a##ci##_4.y), pk2(a##ci##_4.z, a##ci##_4.w), \
                               pk2(a##ci##_5.x, a##ci##_5.y), pk2(a##ci##_5.z, a##ci##_5.w)); \
    aq[base + 48] = make_uint4(pk2(a##ci##_6.x, a##ci##_6.y), pk2(a##ci##_6.z, a##ci##_6.w), \
                               pk2(a##ci##_7.x, a##ci##_7.y), pk2(a##ci##_7.z, a##ci##_7.w)); }

__global__ __launch_bounds__(256, 2) void fused(const ushort* __restrict__ inT,
                                                const float4* __restrict__ pos4,
                                                const int* __restrict__ nn_idx,
                                                const float* __restrict__ dsbuf,
                                                const float* __restrict__ prm_g,
                                                const ushort* __restrict__ LTf,
                                                const float* __restrict__ lin_b,
                                                float* __restrict__ out) {
  __shared__ __align__(16) char smem[16 * XSTR + 16 * WSTR * 4];  // 70656 B
  __shared__ float prms[128];
  char* xraw = smem;
  float* wlds = (float*)(smem + 16 * XSTR);
  int t = threadIdx.x;
  int blk = blockIdx.x;          // 1024 tiles of 16 points
  int b = blk >> 8;
  int n0 = (blk & 255) << 4;
  if (t < 128) prms[t] = prm_g[t];
  __syncthreads();
  // ---- phase 1: stage. thread (k = t>>4, p = t&15) ----
  {
    int k = t >> 4, p = t & 15;
    int r = blk * 16 + p;
    int n = n0 + p;
    int j = nn_idx[(size_t)r * 16 + k];
    float4 pj = pos4[b * NPTS + j];
    float4 pn = pos4[b * NPTS + n];
    float lx = pj.x - pn.x, ly = pj.y - pn.y, lz = pj.z - pn.z;
    float ds = dsbuf[(size_t)r * 16 + k];
    const uint4* srcx = (const uint4*)(inT + ((size_t)(b * NPTS + j)) * 64);
    uint4* dstx = (uint4*)(xraw + p * XSTR + k * 144);
#pragma unroll
    for (int i = 0; i < 8; ++i) dstx[i] = srcx[i];
    float* wr = wlds + p * WSTR + k * 32;
#pragma unroll
    for (int w = 0; w < 32; ++w) {
      float v = fmaf(prms[w * 3], lx,
                fmaf(prms[w * 3 + 1], ly,
                fmaf(prms[w * 3 + 2], lz, prms[96 + w])));
      wr[w] = fmaxf(v, 0.f) * ds;
    }
  }
  __syncthreads();
  // ---- phase 2: feat in NAMED registers. thread (pl = t&15, cl = t>>4) ----
  int pl = t & 15, cl = t >> 4;
  f32x4 a0_0=(f32x4)0.f, a0_1=(f32x4)0.f, a0_2=(f32x4)0.f, a0_3=(f32x4)0.f,
        a0_4=(f32x4)0.f, a0_5=(f32x4)0.f, a0_6=(f32x4)0.f, a0_7=(f32x4)0.f;
  f32x4 a1_0=(f32x4)0.f, a1_1=(f32x4)0.f, a1_2=(f32x4)0.f, a1_3=(f32x4)0.f,
        a1_4=(f32x4)0.f, a1_5=(f32x4)0.f, a1_6=(f32x4)0.f, a1_7=(f32x4)0.f;
  f32x4 a2_0=(f32x4)0.f, a2_1=(f32x4)0.f, a2_2=(f32x4)0.f, a2_3=(f32x4)0.f,
        a2_4=(f32x4)0.f, a2_5=(f32x4)0.f, a2_6=(f32x4)0.f, a2_7=(f32x4)0.f;
  f32x4 a3_0=(f32x4)0.f, a3_1=(f32x4)0.f, a3_2=(f32x4)0.f, a3_3=(f32x4)0.f,
        a3_4=(f32x4)0.f, a3_5=(f32x4)0.f, a3_6=(f32x4)0.f, a3_7=(f32x4)0.f;
  {
    const char* xrow = xraw + pl * XSTR;
    const float* wp = wlds + pl * WSTR;
#pragma unroll 4
    for (int kk = 0; kk < 16; ++kk) {
      unsigned xa = *(const unsigned*)(xrow + kk * 144 + cl * 4);        // ch 2cl,2cl+1
      unsigned xb = *(const unsigned*)(xrow + kk * 144 + 64 + cl * 4);   // ch 32+2cl,33+2cl
      float x0 = __uint_as_float(xa << 16);
      float x1 = __uint_as_float(xa & 0xFFFF0000u);
      float x2 = __uint_as_float(xb << 16);
      float x3 = __uint_as_float(xb & 0xFFFF0000u);
      const f32x4* wk = (const f32x4*)(wp + kk * 32);
      f32x4 W0 = wk[0], W1 = wk[1], W2 = wk[2], W3 = wk[3];
      f32x4 W4 = wk[4], W5 = wk[5], W6 = wk[6], W7 = wk[7];
      FMA_ROW(0)
      FMA_ROW(1)
      FMA_ROW(2)
      FMA_ROW(3)
    }
  }
  __syncthreads();   // everyone done reading xraw/wlds
  // ---- phase 3: write A-frags (bf16) over the staging LDS (64 KB) ----
  uint4* aq = (uint4*)smem;
  WRITE_C(0, 2 * cl)
  WRITE_C(1, 2 * cl + 1)
  WRITE_C(2, 32 + 2 * cl)
  WRITE_C(3, 33 + 2 * cl)
  __syncthreads();
  // ---- phase 4: MFMA GEMM. wave wv owns output tile ot=wv, full K ----
  {
    int wv = t >> 6, l = t & 63;
    const uint4* Lq = (const uint4*)LTf;
    f32x4 cacc = (f32x4)0.f;
#pragma unroll 4
    for (int s = 0; s < 64; ++s) {
      uint4 ua = aq[s * 64 + l];
      uint4 ub = Lq[(s * 4 + wv) * 64 + l];
      bf16x8 A = *reinterpret_cast<bf16x8*>(&ua);
      bf16x8 B = *reinterpret_cast<bf16x8*>(&ub);
      cacc = __builtin_amdgcn_mfma_f32_16x16x32_bf16(A, B, cacc, 0, 0, 0);
    }
    int o = wv * 16 + (l & 15);
    float bias = lin_b[o];
    cacc.x += bias; cacc.y += bias; cacc.z += bias; cacc.w += bias;
    *(f32x4*)(out + ((size_t)(b * 64 + o)) * NPTS + n0 + (l >> 4) * 4) = cacc;
  }
}

// ------------------------------- launch ---------------------------------------
extern "C" void kernel_launch(void* const* d_in, const int* in_sizes, int n_in,
                              void* d_out, int out_size, void* d_ws, size_t ws_size,
                              hipStream_t stream) {
  (void)in_sizes; (void)n_in; (void)out_size; (void)ws_size;
  const float* inputs = (const float*)d_in[0];
  const float* pos    = (const float*)d_in[1];
  const float* invd   = (const float*)d_in[2];
  const float* wn_w   = (const float*)d_in[3];
  const float* wn_g   = (const float*)d_in[5];
  const float* wn_be  = (const float*)d_in[6];
  const float* dn_w1  = (const float*)d_in[7];
  const float* dn_g1  = (const float*)d_in[9];
  const float* dn_be1 = (const float*)d_in[10];
  const float* dn_w2  = (const float*)d_in[11];
  const float* dn_b2  = (const float*)d_in[12];
  const float* lin_w  = (const float*)d_in[13];
  const float* lin_b  = (const float*)d_in[14];
  float* outp = (float*)d_out;

  char* ws = (char*)d_ws;
  double*   stp      = (double*)(ws + 294912);                // 32 KB  (256 x 16 dbl)
  float*    prm      = (float*)(ws + 1024);                   // 640 B
  float4*   pos4     = (float4*)(ws + 4096);                  // 256 KB
  int*      nnidx    = (int*)(ws + (size_t)(1u << 19));       // 1 MB   [0.5, 1.5)
  float*    dsbuf    = (float*)(ws + (size_t)(3u << 19));     // 1 MB   [1.5, 2.5)
  ushort*   inT      = (ushort*)(ws + (size_t)(5u << 19));    // 2 MB   [2.5, 4.5)
  ushort*   LTf      = (ushort*)(ws + (size_t)(9u << 19));    // 256 KB [4.5, 4.75)
  unsigned* T0g      = (unsigned*)(ws + (size_t)(19u << 18)); // 64 KB  [4.75, ...)
  uint4*    partials = (uint4*)(ws + (size_t)(11u << 19));    // 8 MB   [5.5, 13.5)
  uint4*    surv     = (uint4*)(ws + (size_t)(11u << 19));    // 16 MB  [5.5, 21.5) aliases dead partials

  pack_pos4<<<64, 256, 0, stream>>>(pos, pos4);
  transpose_in<<<256, 256, 0, stream>>>(inputs, inT);
  prep_LTf<<<64, 256, 0, stream>>>(lin_w, LTf);
  knn_sub<<<dim3(64, 8), 256, 0, stream>>>(pos4, partials);
  knn_thresh<<<256, 64, 0, stream>>>(partials, T0g);
  knn_filter<<<dim3(64, 16), 256, 0, stream>>>(pos4, T0g, surv);
  knn_final<<<256, 64, 0, stream>>>(pos4, invd, surv, nnidx, dsbuf, stp);
  finalize_params<<<1, 64, 0, stream>>>(stp, wn_w, wn_g, wn_be, dn_w1, dn_g1, dn_be1, prm);
  ds_kernel<<<64, 256, 0, stream>>>(dsbuf, prm, dn_w2, dn_b2);
  fused<<<1024, 256, 0, stream>>>(inT, pos4, nnidx, dsbuf, prm, LTf, lin_b, outp);
}